// Round 13
// baseline (16228.972 us; speedup 1.0000x reference)
//
#include <hip/hip_runtime.h>
#include <hip/hip_bf16.h>
#include <math.h>

#define BB 128
#define TT 256
#define IDIM 64
#define HD 128
#define G4 512
#define OC 100
#define W1 62
#define W2 60
#define W3 58
#define NPX1 (W1*W1)
#define NPX2 (W2*W2)
#define NPX3 (W3*W3)
#define SS NPX3
#define FF (SS + 2*HD)
#define HIDN 1810
#define ANF 64

typedef __hip_bfloat16 bf16;
typedef _Float16 f16;
typedef __attribute__((ext_vector_type(8))) short bf16x8;
typedef __attribute__((ext_vector_type(4))) short bf16x4;
typedef __attribute__((ext_vector_type(2))) _Float16 half2v;
typedef __attribute__((ext_vector_type(4))) float f32x4;

__device__ __forceinline__ float ldf(const float* p) { return *p; }
__device__ __forceinline__ float ldf(const bf16* p)  { return __bfloat162float(*p); }
__device__ __forceinline__ void  stf(float* p, float v) { *p = v; }
__device__ __forceinline__ void  stf(bf16* p, float v)  { *p = __float2bfloat16(v); }

__device__ __forceinline__ short f2bs(float v) {
    bf16 t = __float2bfloat16(v); short s; __builtin_memcpy(&s, &t, 2); return s;
}
__device__ __forceinline__ float fsig(float x) {
    return __builtin_amdgcn_rcpf(1.f + __expf(-x));
}
__device__ __forceinline__ float ftanh(float x) {
    float t = __expf(-2.f * fabsf(x));
    float r = __builtin_amdgcn_rcpf(1.f + t);
    float m = 1.f - 2.f * t * r;
    return copysignf(m, x);
}
// packed f16 dual-FMA: clang folds (float)f16 * (float)f16 + f32 into v_fma_mix_f32
__device__ __forceinline__ float fmix2(unsigned w, unsigned h, float acc) {
    half2v wv, hv;
    __builtin_memcpy(&wv, &w, 4);
    __builtin_memcpy(&hv, &h, 4);
    acc = fmaf((float)wv[0], (float)hv[0], acc);
    acc = fmaf((float)wv[1], (float)hv[1], acc);
    return acc;
}

__device__ __forceinline__ bf16x8 load8(const bf16* p) { return *(const bf16x8*)p; }
__device__ __forceinline__ bf16x8 load8(const float* p) {
    float4 x = *(const float4*)p;
    float4 y = *(const float4*)(p + 4);
    bf16x8 r;
    r[0] = f2bs(x.x); r[1] = f2bs(x.y); r[2] = f2bs(x.z); r[3] = f2bs(x.w);
    r[4] = f2bs(y.x); r[5] = f2bs(y.y); r[6] = f2bs(y.z); r[7] = f2bs(y.w);
    return r;
}

__global__ void zero_kernel(float* o, int n)
{
    int i = blockIdx.x * 256 + threadIdx.x;
    if (i < n) o[i] = 0.f;
}

// ---------------- fused preprocessing: all converts/repacks in ONE launch ----------------
__device__ __forceinline__ void body_cvt_bf16(const float* __restrict__ s, bf16* __restrict__ d,
                                              int i, int n4)
{
    if (i >= n4) return;
    float4 v = ((const float4*)s)[i];
    bf16x4 o;
    o[0] = f2bs(v.x); o[1] = f2bs(v.y); o[2] = f2bs(v.z); o[3] = f2bs(v.w);
    *(bf16x4*)(d + 4 * (size_t)i) = o;
}
__device__ __forceinline__ void body_cvt_f16(const float* __restrict__ s, f16* __restrict__ d,
                                             int i, int n4)
{
    if (i >= n4) return;
    float4 v = ((const float4*)s)[i];
    f16 o[4] = {(f16)v.x, (f16)v.y, (f16)v.z, (f16)v.w};
    *(uint2*)(d + 4 * (size_t)i) = *(uint2*)o;
}
__device__ __forceinline__ void body_wt(const float* __restrict__ w, bf16* __restrict__ WT, int idx)
{
    if (idx >= 129024) return;   // 9*4*112*32
    int i  = idx & 31;
    int oc = (idx >> 5) % 112;
    int ts = idx / (112 * 32);
    int s = ts & 3, t = ts >> 2;
    int ic = s * 32 + i;
    float v = 0.f;
    if (oc < OC && ic < OC) v = w[(oc * OC + ic) * 9 + t];
    WT[idx] = __float2bfloat16(v);
}

__global__ __launch_bounds__(256)
void prep_kernel(const float* __restrict__ x2,   bf16* __restrict__ X2B,
                 const float* __restrict__ whh0, f16*  __restrict__ LWf0,
                 const float* __restrict__ whh1, f16*  __restrict__ LWf1,
                 const float* __restrict__ wih0, bf16* __restrict__ WIH0B,
                 const float* __restrict__ wih1, f16*  __restrict__ WX1f,
                 const float* __restrict__ a1w,  bf16* __restrict__ A1WB,
                 const float* __restrict__ bih0, const float* __restrict__ bhh0, float* __restrict__ BS0,
                 const float* __restrict__ bih1, const float* __restrict__ bhh1, float* __restrict__ BS1,
                 const float* __restrict__ c2aw, bf16* __restrict__ WTa,
                 const float* __restrict__ c2bw, bf16* __restrict__ WTb)
{
    int bid = blockIdx.x;
    int tid = threadIdx.x;
    if (bid < 2048)      body_cvt_bf16(x2,   X2B,   bid * 256 + tid, 524288);
    else if (bid < 2112) body_cvt_f16 (whh0, LWf0, (bid - 2048) * 256 + tid, 16384);
    else if (bid < 2176) body_cvt_f16 (whh1, LWf1, (bid - 2112) * 256 + tid, 16384);
    else if (bid < 2208) body_cvt_bf16(wih0, WIH0B, (bid - 2176) * 256 + tid, 8192);
    else if (bid < 2272) body_cvt_f16 (wih1, WX1f, (bid - 2208) * 256 + tid, 16384);
    else if (bid < 2499) body_cvt_bf16(a1w,  A1WB,  (bid - 2272) * 256 + tid, 57920);
    else if (bid < 2500) { BS0[tid] = bih0[tid] + bhh0[tid]; BS0[tid + 256] = bih0[tid + 256] + bhh0[tid + 256]; }
    else if (bid < 2501) { BS1[tid] = bih1[tid] + bhh1[tid]; BS1[tid + 256] = bih1[tid + 256] + bhh1[tid + 256]; }
    else if (bid < 3005) body_wt(c2aw, WTa, (bid - 2501) * 256 + tid);
    else                 body_wt(c2bw, WTb, (bid - 3005) * 256 + tid);
}

// ---------------- conv1: [nb,3,64,64] -> relu -> [nb,100,62,62] (bf16 out) ----------------
__global__ __launch_bounds__(256)
void conv1_kernel(const float* __restrict__ x1,
                  const float* __restrict__ w,     // [100,3,3,3]
                  const float* __restrict__ bias,  // [100]
                  bf16* __restrict__ out)          // [nb,100,62,62]
{
    __shared__ float wl[2700];
    __shared__ float bl[OC];
    int tid = threadIdx.x;
    for (int i = tid; i < 2700; i += 256) wl[i] = w[i];
    if (tid < OC) bl[tid] = bias[tid];
    __syncthreads();
    int b  = blockIdx.x;
    int px = blockIdx.y * 256 + tid;
    if (px >= NPX1) return;
    int y = px / W1, x = px % W1;
    float in[3][3][3];
    const float* xb = x1 + (size_t)b * 3 * 64 * 64;
#pragma unroll
    for (int ic = 0; ic < 3; ic++)
#pragma unroll
        for (int r = 0; r < 3; r++)
#pragma unroll
            for (int c = 0; c < 3; c++)
                in[ic][r][c] = xb[(ic * 64 + y + r) * 64 + x + c];
    bf16* ob = out + (size_t)b * OC * NPX1 + px;
    for (int oc = 0; oc < OC; ++oc) {
        float acc = bl[oc];
        const float* wp = &wl[oc * 27];
#pragma unroll
        for (int ic = 0; ic < 3; ic++)
#pragma unroll
            for (int r = 0; r < 3; r++)
#pragma unroll
                for (int c = 0; c < 3; c++)
                    acc = fmaf(in[ic][r][c], wp[ic * 9 + r * 3 + c], acc);
        ob[(size_t)oc * NPX1] = __float2bfloat16(fmaxf(acc, 0.f));
    }
}

// ---------------- conv2 via MFMA implicit GEMM (lane-ordered wl; r11 bank fix) ----------------
__global__ __launch_bounds__(512, 1)
void conv2_mfma(const bf16* __restrict__ in,   // [nb,100,iw,iw]
                const bf16* __restrict__ WT,   // [9][4][112][32] bf16
                const float* __restrict__ bias,
                bf16* __restrict__ out,        // [nb,100,ow,ow]
                int iw, int ow)
{
    __shared__ bf16 il[10 * 72 * 40];          // 57.6 KB
    __shared__ bf16 wl[4032 * 8];              // 64.5 KB
    int tid = threadIdx.x;
    int b = blockIdx.x;
    int y0 = blockIdx.y * 8;
    int wid = tid >> 6;
    int l = tid & 63;
    int hq = l >> 4;
    int l16 = l & 15;
    int yo = y0 + wid;

    f32x4 acc[7][4];
#pragma unroll
    for (int f = 0; f < 7; f++) {
#pragma unroll
        for (int r = 0; r < 4; r++) {
            int oc = f * 16 + hq * 4 + r;
            float bv = (oc < OC) ? bias[oc] : 0.f;
#pragma unroll
            for (int n = 0; n < 4; n++) acc[f][n][r] = bv;
        }
    }

    const size_t ims = (size_t)iw * iw;
    int icl = tid & 31;
    int t2  = tid >> 5;
    for (int s = 0; s < 4; ++s) {
        __syncthreads();
        int ic = s * 32 + icl;
        bool icok = ic < OC;
        const bf16* ibase = in + (size_t)(b * OC + ic) * ims;
#pragma unroll
        for (int it = 0; it < 6; ++it) {
            int u2 = t2 + it * 16;
            if (u2 < 90) {
                int r = u2 / 9, xb = u2 - r * 9;
                int x8 = xb * 8;
                int yy = y0 + r;
                bf16x8 v = {0, 0, 0, 0, 0, 0, 0, 0};
                if (icok && yy < iw && x8 < iw) {
                    const short* sp = (const short*)(ibase + (size_t)yy * iw + x8);
                    if (x8 + 8 <= iw) {
                        const unsigned* sp32 = (const unsigned*)sp;
#pragma unroll
                        for (int q = 0; q < 4; q++)
                            ((unsigned*)&v)[q] = sp32[q];
                    } else {
                        for (int k = 0; k < 8; k++)
                            if (x8 + k < iw) ((short*)&v)[k] = sp[k];
                    }
                }
                bf16* dst = &il[(r * 72 + x8) * 40 + icl];
#pragma unroll
                for (int k = 0; k < 8; k++)
                    *(short*)&dst[k * 40] = ((short*)&v)[k];
            }
        }
#pragma unroll
        for (int it = 0; it < 8; ++it) {
            int u = tid + it * 512;            // over 9*7*64 = 4032 units
            if (u < 4032) {
                int tf = u >> 6; int lp = u & 63;
                int t = tf / 7, f = tf - t * 7;
                int oc = f * 16 + (lp & 15);
                int hq2 = lp >> 4;
                *(bf16x8*)&wl[(size_t)u * 8] =
                    *(const bf16x8*)(WT + (size_t)((t * 4 + s) * 112 + oc) * 32 + hq2 * 8);
            }
        }
        __syncthreads();

#pragma unroll
        for (int ky = 0; ky < 3; ++ky) {
#pragma unroll
            for (int kx = 0; kx < 3; ++kx) {
                int t = ky * 3 + kx;
                bf16x8 a[7];
#pragma unroll
                for (int f = 0; f < 7; f++)
                    a[f] = *(const bf16x8*)&wl[(size_t)((t * 7 + f) * 64 + l) * 8];
                bf16x8 bfr[4];
#pragma unroll
                for (int n = 0; n < 4; n++)
                    bfr[n] = *(const bf16x8*)&il[((wid + ky) * 72 + kx + l16 + n * 16) * 40 + hq * 8];
#pragma unroll
                for (int f = 0; f < 7; f++)
#pragma unroll
                    for (int n = 0; n < 4; n++)
                        acc[f][n] = __builtin_amdgcn_mfma_f32_16x16x32_bf16(
                            a[f], bfr[n], acc[f][n], 0, 0, 0);
            }
        }
    }

    if (yo < ow) {
#pragma unroll
        for (int f = 0; f < 7; f++) {
#pragma unroll
            for (int r = 0; r < 4; r++) {
                int oc = f * 16 + hq * 4 + r;
                if (oc < OC) {
#pragma unroll
                    for (int n = 0; n < 4; n++) {
                        int x = n * 16 + l16;
                        if (x < ow)
                            out[((size_t)(b * OC + oc) * ow + yo) * ow + x] =
                                __float2bfloat16(fmaxf(acc[f][n][r], 0.f));
                    }
                }
            }
        }
    }
}

// ---------------- generic MFMA GEMM: C[M,N] = A[M,K] @ B[N,K]^T (+bias, +relu) ----------------
template<typename TB, typename TC, int ACT>
__global__ __launch_bounds__(256)
void gemm_mfma(const bf16* __restrict__ A, int lda,
               const TB* __restrict__ B, int ldb,
               const float* __restrict__ bias,
               TC* __restrict__ C, int ldc,
               int M, int N, int K)
{
    __shared__ bf16 As[64 * 72];
    __shared__ bf16 Bs[64 * 72];
    int tid = threadIdx.x;
    int l = tid & 63, wid = tid >> 6;
    int l16 = l & 15, h = l >> 4;
    int m0 = blockIdx.x * 64, n0 = blockIdx.y * 64;
    f32x4 acc[4];
#pragma unroll
    for (int nb = 0; nb < 4; nb++) acc[nb] = (f32x4){0.f, 0.f, 0.f, 0.f};

    int rs = tid >> 3;
    int kc = (tid & 7) * 8;

    for (int k0 = 0; k0 < K; k0 += 64) {
        int kr = K - k0;
#pragma unroll
        for (int half = 0; half < 2; half++) {
            int rr = rs + half * 32;
            bf16x8 av = {0, 0, 0, 0, 0, 0, 0, 0};
            int m = m0 + rr;
            if (m < M) {
                const short* src = (const short*)(A + (size_t)m * lda + k0 + kc);
                if (kc + 8 <= kr) av = *(const bf16x8*)src;
                else if (kc < kr) {
                    for (int j = 0; j < 8; j++) if (kc + j < kr) ((short*)&av)[j] = src[j];
                }
            }
            *(bf16x8*)&As[rr * 72 + kc] = av;
            bf16x8 bv = {0, 0, 0, 0, 0, 0, 0, 0};
            int n = n0 + rr;
            if (n < N) {
                const TB* src = B + (size_t)n * ldb + k0 + kc;
                if (kc + 8 <= kr) bv = load8(src);
                else if (kc < kr) {
                    for (int j = 0; j < 8; j++) if (kc + j < kr) ((short*)&bv)[j] = f2bs(ldf(src + j));
                }
            }
            *(bf16x8*)&Bs[rr * 72 + kc] = bv;
        }
        __syncthreads();
#pragma unroll
        for (int kk = 0; kk < 2; kk++) {
            bf16x8 af = *(const bf16x8*)&As[(wid * 16 + l16) * 72 + kk * 32 + h * 8];
#pragma unroll
            for (int nb = 0; nb < 4; nb++) {
                bf16x8 bfr = *(const bf16x8*)&Bs[(nb * 16 + l16) * 72 + kk * 32 + h * 8];
                acc[nb] = __builtin_amdgcn_mfma_f32_16x16x32_bf16(af, bfr, acc[nb], 0, 0, 0);
            }
        }
        __syncthreads();
    }
#pragma unroll
    for (int nb = 0; nb < 4; nb++) {
        int col = n0 + nb * 16 + l16;
        if (col >= N) continue;
        float bv = bias ? bias[col] : 0.f;
#pragma unroll
        for (int reg = 0; reg < 4; reg++) {
            int row = m0 + wid * 16 + h * 4 + reg;
            if (row < M) {
                float v = acc[nb][reg] + bv;
                if (ACT == 1) v = fmaxf(v, 0.f);
                stf(&C[(size_t)row * ldc + col], v);
            }
        }
    }
}

// ---------------- small fp32 GEMM (kept for tiny HB matmul) ----------------
template<typename TA, typename TC, int BM, int BN, int BK, int TM, int TN, int ACT>
__global__ __launch_bounds__((BM / TM) * (BN / TN))
void gemm_tn(const TA* __restrict__ A, int lda,
             const float* __restrict__ Bmat, int ldb,
             const float* __restrict__ bias,
             TC* __restrict__ C, int ldc,
             int M, int N, int K)
{
    constexpr int TX = BN / TN;
    constexpr int TY = BM / TM;
    constexpr int NT = TX * TY;
    __shared__ float As[BK][BM + 1];
    __shared__ float Bs[BK][BN + 1];
    int tid = threadIdx.x;
    int tx = tid % TX, ty = tid / TX;
    int m0 = blockIdx.x * BM, n0 = blockIdx.y * BN;
    float acc[TM][TN] = {};
    for (int k0 = 0; k0 < K; k0 += BK) {
        for (int idx = tid; idx < BM * BK; idx += NT) {
            int i = idx / BK, j = idx % BK;
            int m = m0 + i, k = k0 + j;
            As[j][i] = (m < M && k < K) ? ldf(&A[(size_t)m * lda + k]) : 0.f;
        }
        for (int idx = tid; idx < BN * BK; idx += NT) {
            int i = idx / BK, j = idx % BK;
            int n = n0 + i, k = k0 + j;
            Bs[j][i] = (n < N && k < K) ? Bmat[(size_t)n * ldb + k] : 0.f;
        }
        __syncthreads();
#pragma unroll
        for (int k = 0; k < BK; ++k) {
            float av[TM], bv[TN];
#pragma unroll
            for (int i = 0; i < TM; i++) av[i] = As[k][ty * TM + i];
#pragma unroll
            for (int j = 0; j < TN; j++) bv[j] = Bs[k][tx * TN + j];
#pragma unroll
            for (int i = 0; i < TM; i++)
#pragma unroll
                for (int j = 0; j < TN; j++)
                    acc[i][j] += av[i] * bv[j];
        }
        __syncthreads();
    }
#pragma unroll
    for (int i = 0; i < TM; i++) {
        int m = m0 + ty * TM + i;
        if (m >= M) continue;
#pragma unroll
        for (int j = 0; j < TN; j++) {
            int n = n0 + tx * TN + j;
            if (n >= N) continue;
            float v = acc[i][j] + (bias ? bias[n] : 0.f);
            if (ACT == 1) v = fmaxf(v, 0.f);
            stf(&C[(size_t)m * ldc + n], v);
        }
    }
}

// ---------------- fused 2-layer LSTM: software-pipelined recurrence ----------------
// 128 blocks x 512 thr. Iteration k computes layer0 step k AND layer1 step k-1
// (layer1's input IS layer0's h). Thread g holds whh0/wih1/whh1 row g in VGPRs
// (3x64=192, pinned). Phase B: waves0-1 update h0, waves2-3 update h1 (parallel).
// Kills: 2nd lstm launch, layer1 gate-GEMM, Y0 traffic; steps 512+gemm -> 257.
__global__ __launch_bounds__(512, 1)
void lstm_fused(const bf16* __restrict__ G,    // [B,T,512] layer0 x-part (+bias0)
                const f16* __restrict__ W0,    // whh0 [512,128] f16
                const f16* __restrict__ W1x,   // wih1 [512,128] f16
                const f16* __restrict__ W1h,   // whh1 [512,128] f16
                const float* __restrict__ BS1, // [512] bih1+bhh1
                float* __restrict__ HN)        // [B,256]
{
    __shared__ __align__(16) f16 h0l[HD];
    __shared__ __align__(16) f16 h1l[HD];
    __shared__ float ex0[G4];
    __shared__ float ex1[G4];
    int g = threadIdx.x;
    int b = blockIdx.x;
    uint4 w0[16], wx[16], wh[16];              // 3 x 64 VGPR of f16 weights
    const uint4* p0 = (const uint4*)(W0  + (size_t)g * HD);
    const uint4* px = (const uint4*)(W1x + (size_t)g * HD);
    const uint4* ph = (const uint4*)(W1h + (size_t)g * HD);
#pragma unroll
    for (int q = 0; q < 16; q++) { w0[q] = p0[q]; wx[q] = px[q]; wh[q] = ph[q]; }
#pragma unroll
    for (int q = 0; q < 16; q++) {
        asm volatile("" : "+v"(w0[q].x), "+v"(w0[q].y), "+v"(w0[q].z), "+v"(w0[q].w));
        asm volatile("" : "+v"(wx[q].x), "+v"(wx[q].y), "+v"(wx[q].z), "+v"(wx[q].w));
        asm volatile("" : "+v"(wh[q].x), "+v"(wh[q].y), "+v"(wh[q].z), "+v"(wh[q].w));
    }
    float bs1 = BS1[g];
    float c = 0.f;                             // layer0 cell (g<128) / layer1 cell (128<=g<256)
    if (g < HD) { h0l[g] = (f16)0.f; h1l[g] = (f16)0.f; }
    __syncthreads();
    const bf16* Gb = G + (size_t)b * TT * G4 + g;
    float gcur = __bfloat162float(Gb[0]);
    bool sig = (g < 2 * HD || g >= 3 * HD);
    for (int k = 0; k <= TT; ++k) {
        int tn = (k + 1 < TT) ? k + 1 : TT - 1;
        bf16 gnext = Gb[(size_t)tn * G4];      // prefetch
        float a0 = 0.f, a1 = 0.f, a2 = 0.f, a3 = 0.f;   // layer0 h-dot
        float d0 = 0.f, d1 = 0.f, d2 = 0.f, d3 = 0.f;   // layer1 x-dot + h-dot
#pragma unroll
        for (int q = 0; q < 16; q++) {
            uint4 h0w = *(const uint4*)&h0l[q * 8];
            a0 = fmix2(w0[q].x, h0w.x, a0);
            a1 = fmix2(w0[q].y, h0w.y, a1);
            a2 = fmix2(w0[q].z, h0w.z, a2);
            a3 = fmix2(w0[q].w, h0w.w, a3);
            d0 = fmix2(wx[q].x, h0w.x, d0);
            d1 = fmix2(wx[q].y, h0w.y, d1);
            d2 = fmix2(wx[q].z, h0w.z, d2);
            d3 = fmix2(wx[q].w, h0w.w, d3);
            uint4 h1w = *(const uint4*)&h1l[q * 8];
            d0 = fmix2(wh[q].x, h1w.x, d0);
            d1 = fmix2(wh[q].y, h1w.y, d1);
            d2 = fmix2(wh[q].z, h1w.z, d2);
            d3 = fmix2(wh[q].w, h1w.w, d3);
        }
        float dotA = gcur + (a0 + a1) + (a2 + a3);
        float dotB = bs1 + (d0 + d1) + (d2 + d3);
        ex0[g] = sig ? fsig(dotA) : ftanh(dotA);
        ex1[g] = sig ? fsig(dotB) : ftanh(dotB);
        gcur = __bfloat162float(gnext);
        __syncthreads();                       // ex ready
        if (g < HD) {
            if (k < TT) {                      // layer0 step k
                float iv = ex0[g], fv = ex0[HD + g], gv = ex0[2 * HD + g], ov = ex0[3 * HD + g];
                c = fv * c + iv * gv;
                float nh = ov * ftanh(c);
                h0l[g] = (f16)nh;
                if (k == TT - 1) HN[(size_t)b * 256 + g] = nh;
            }
        } else if (g < 2 * HD) {
            int u = g - HD;
            if (k >= 1) {                      // layer1 step k-1
                float iv = ex1[u], fv = ex1[HD + u], gv = ex1[2 * HD + u], ov = ex1[3 * HD + u];
                c = fv * c + iv * gv;
                float nh = ov * ftanh(c);
                h1l[u] = (f16)nh;
                if (k == TT) HN[(size_t)b * 256 + HD + u] = nh;
            }
        }
        __syncthreads();                       // h ready for next iter
    }
}

// ---------------- small helpers ----------------
__global__ __launch_bounds__(128)
void attn_softmax(const float* __restrict__ T1,  // [nb*OC,64]
                  const float* __restrict__ HB,  // [nb,64] (chunk base, includes attn1_b)
                  const float* __restrict__ a2w, // [64]
                  const float* __restrict__ a2b, // [1]
                  float* __restrict__ ATT)       // [nb,100]
{
    __shared__ float hbl[ANF];
    __shared__ float awl[ANF];
    __shared__ float red[128];
    int b = blockIdx.x, tid = threadIdx.x;
    if (tid < ANF) { hbl[tid] = HB[b * ANF + tid]; awl[tid] = a2w[tid]; }
    __syncthreads();
    float lg = -1e30f;
    if (tid < OC) {
        const float* tp = T1 + (size_t)(b * OC + tid) * ANF;
        float s = 0.f;
#pragma unroll 4
        for (int j = 0; j < ANF; j++) s += ftanh(tp[j] + hbl[j]) * awl[j];
        lg = s + a2b[0];
    }
    red[tid] = lg; __syncthreads();
    for (int st = 64; st > 0; st >>= 1) { if (tid < st) red[tid] = fmaxf(red[tid], red[tid + st]); __syncthreads(); }
    float mx = red[0]; __syncthreads();
    float e = (tid < OC) ? __expf(lg - mx) : 0.f;
    red[tid] = e; __syncthreads();
    for (int st = 64; st > 0; st >>= 1) { if (tid < st) red[tid] += red[tid + st]; __syncthreads(); }
    if (tid < OC) ATT[b * OC + tid] = e / red[0];
}

__global__ __launch_bounds__(256)
void ctx_concat(const bf16* __restrict__ XD,   // [nb,100,3364]
                const float* __restrict__ ATT, // [nb,100]
                const float* __restrict__ HN,  // [nb,256] (chunk base)
                bf16* __restrict__ M)          // [nb,3620] bf16 (chunk base)
{
    __shared__ float al[OC];
    int b = blockIdx.x;
    int tid = threadIdx.x;
    if (tid < OC) al[tid] = ATT[b * OC + tid];
    __syncthreads();
    int s = blockIdx.y * 256 + tid;
    if (s < SS) {
        const bf16* xp = XD + (size_t)b * OC * SS + s;
        float acc = 0.f;
#pragma unroll 4
        for (int c = 0; c < OC; c++) acc = fmaf(__bfloat162float(xp[(size_t)c * SS]), al[c], acc);
        M[(size_t)b * FF + s] = __float2bfloat16(acc);
    } else if (s < FF) {
        M[(size_t)b * FF + s] = __float2bfloat16(HN[b * 256 + (s - SS)]);
    }
}

__global__ __launch_bounds__(256)
void fc2_kernel(const float* __restrict__ H1, // [128,1810]
                const float* __restrict__ w,  // [1810]
                const float* __restrict__ bias,
                float* __restrict__ out)      // [128]
{
    int tid = threadIdx.x;
    int lane = tid & 63, wid = tid >> 6;
    int b = blockIdx.x * 4 + wid;
    float acc = 0.f;
    for (int j = lane; j < HIDN; j += 64) acc = fmaf(H1[(size_t)b * HIDN + j], w[j], acc);
#pragma unroll
    for (int off = 32; off > 0; off >>= 1) acc += __shfl_down(acc, off, 64);
    if (lane == 0) out[b] = acc + bias[0];
}

extern "C" void kernel_launch(void* const* d_in, const int* in_sizes, int n_in,
                              void* d_out, int out_size, void* d_ws, size_t ws_size,
                              hipStream_t stream)
{
    const float* x1   = (const float*)d_in[0];
    const float* x2   = (const float*)d_in[1];
    const float* c1w  = (const float*)d_in[2];
    const float* c1b  = (const float*)d_in[3];
    const float* c2aw = (const float*)d_in[4];
    const float* c2ab = (const float*)d_in[5];
    const float* c2bw = (const float*)d_in[6];
    const float* c2bb = (const float*)d_in[7];
    const float* wih0 = (const float*)d_in[8];
    const float* whh0 = (const float*)d_in[9];
    const float* bih0 = (const float*)d_in[10];
    const float* bhh0 = (const float*)d_in[11];
    const float* wih1 = (const float*)d_in[12];
    const float* whh1 = (const float*)d_in[13];
    const float* bih1 = (const float*)d_in[14];
    const float* bhh1 = (const float*)d_in[15];
    const float* a1w  = (const float*)d_in[16];
    const float* a1b  = (const float*)d_in[17];
    const float* a2w  = (const float*)d_in[18];
    const float* a2b  = (const float*)d_in[19];
    const float* f1w  = (const float*)d_in[20];
    const float* f1b  = (const float*)d_in[21];
    const float* f2w  = (const float*)d_in[22];
    const float* f2b  = (const float*)d_in[23];
    float* out = (float*)d_out;

    // ---- LSTM-phase overlay (fixed offsets; dead once CNN phase starts) ----
    char* base = (char*)d_ws;
    bf16* G0    = (bf16*)(base + 0);            // 33,554,432
    bf16* X2B   = (bf16*)(base + 41943040);     //  4,194,304
    bf16* WIH0B = (bf16*)(base + 46137344);     //     65,536
    f16*  WX1f  = (f16*)(base + 46202880);      //    131,072 (f16 wih1)
    f16*  LWf0  = (f16*)(base + 46333952);      //    131,072 (f16 whh0)
    f16*  LWf1  = (f16*)(base + 46465024);      //    131,072 (end 46,596,096)
    const size_t LSTM_END = 46596096;

    // ---- pick CNN batch-chunk size from available workspace ----
    int nb = 0; size_t ov = 0;
    for (int cand = BB; cand >= 32; cand >>= 1) {
        size_t cnn = (size_t)cand * OC * (NPX1 + NPX2) * 2;
        size_t o = cnn > LSTM_END ? cnn : LSTM_END;
        size_t q = o + 2048 + 2048 + 131072 + 32768
                 + (size_t)cand * OC * 64 * 4                      // T1c
                 + (((size_t)cand * OC * 4 + 255) & ~(size_t)255)  // ATTc
                 + 926720 + 926720 + 258048 + 258048 + 463360;
        if (ws_size >= q) { nb = cand; ov = o; break; }
    }
    if (nb == 0) {
        zero_kernel<<<1, 128, 0, stream>>>(out, out_size);
        return;
    }
    bf16* A1c = (bf16*)(base + 0);
    bf16* A2c = (bf16*)(base + (size_t)nb * OC * NPX1 * 2);
    bf16* XDc = A1c;
    size_t p = ov;
    float* BS0  = (float*)(base + p); p += 2048;
    float* BS1  = (float*)(base + p); p += 2048;
    float* HN   = (float*)(base + p); p += 131072;   // 128*256*4
    float* HB   = (float*)(base + p); p += 32768;    // 128*64*4
    float* T1c  = (float*)(base + p); p += (size_t)nb * OC * 64 * 4;
    float* ATTc = (float*)(base + p); p += ((size_t)nb * OC * 4 + 255) & ~(size_t)255;
    bf16*  MBb  = (bf16*)(base + p); p += 926720;    // 128*3620*2
    float* H1   = (float*)(base + p); p += 926720;   // 128*1810*4
    bf16* WTa   = (bf16*)(base + p); p += 258048;
    bf16* WTb   = (bf16*)(base + p); p += 258048;
    bf16* A1WB  = (bf16*)(base + p); p += 463360;    // 64*3620*2

    // ---- fused preprocessing (1 launch) ----
    prep_kernel<<<3509, 256, 0, stream>>>(
        x2, X2B, whh0, LWf0, whh1, LWf1, wih0, WIH0B, wih1, WX1f, a1w, A1WB,
        bih0, bhh0, BS0, bih1, bhh1, BS1, c2aw, WTa, c2bw, WTb);

    // ---- LSTM branch: gate GEMM (layer0 x-part) + fused 2-layer recurrence ----
    gemm_mfma<bf16, bf16, 0><<<dim3(512, 8), 256, 0, stream>>>(
        X2B, IDIM, WIH0B, IDIM, BS0, G0, G4, BB * TT, G4, IDIM);
    lstm_fused<<<BB, 512, 0, stream>>>(G0, LWf0, WX1f, LWf1, BS1, HN);

    // hn-part of attention layer 1 (full batch, once; tiny fp32)
    gemm_tn<float, float, 32, 32, 16, 2, 2, 0><<<dim3(4, 2), 256, 0, stream>>>(
        HN, 256, a1w + SS, FF, a1b, HB, ANF, BB, ANF, 256);

    // ---- CNN branch + attention + ctx, chunked over batch (nb rows/chunk) ----
    for (int c0 = 0; c0 < BB; c0 += nb) {
        conv1_kernel<<<dim3(nb, 16), 256, 0, stream>>>(
            x1 + (size_t)c0 * 3 * 64 * 64, c1w, c1b, A1c);
        conv2_mfma<<<dim3(nb, 8), 512, 0, stream>>>(A1c, WTa, c2ab, A2c, W1, W2);
        conv2_mfma<<<dim3(nb, 8), 512, 0, stream>>>(A2c, WTb, c2bb, XDc, W2, W3);
        gemm_mfma<bf16, float, 0><<<dim3(nb * OC / 64, 1), 256, 0, stream>>>(
            XDc, SS, A1WB, FF, nullptr, T1c, ANF, nb * OC, ANF, SS);
        attn_softmax<<<nb, 128, 0, stream>>>(T1c, HB + (size_t)c0 * ANF, a2w, a2b, ATTc);
        ctx_concat<<<dim3(nb, 15), 256, 0, stream>>>(
            XDc, ATTc, HN + (size_t)c0 * 256, MBb + (size_t)c0 * FF);
    }

    // ---- fusion MLP (fc1 converts f32 B during staging) ----
    gemm_mfma<float, float, 1><<<dim3(2, 29), 256, 0, stream>>>(
        MBb, FF, f1w, FF, f1b, H1, HIDN, BB, HIDN, FF);
    fc2_kernel<<<BB / 4, 256, 0, stream>>>(H1, f2w, f2b, out);
}

// Round 15
// 1098.463 us; speedup vs baseline: 14.7743x; 14.7743x over previous
//
#include <hip/hip_runtime.h>
#include <hip/hip_bf16.h>
#include <math.h>

#define BB 128
#define TT 256
#define IDIM 64
#define HD 128
#define G4 512
#define OC 100
#define W1 62
#define W2 60
#define W3 58
#define NPX1 (W1*W1)
#define NPX2 (W2*W2)
#define NPX3 (W3*W3)
#define SS NPX3
#define FF (SS + 2*HD)
#define HIDN 1810
#define ANF 64

typedef __hip_bfloat16 bf16;
typedef _Float16 f16;
typedef __attribute__((ext_vector_type(8))) short bf16x8;
typedef __attribute__((ext_vector_type(4))) short bf16x4;
typedef __attribute__((ext_vector_type(2))) _Float16 half2v;
typedef __attribute__((ext_vector_type(4))) float f32x4;

__device__ __forceinline__ float ldf(const float* p) { return *p; }
__device__ __forceinline__ float ldf(const bf16* p)  { return __bfloat162float(*p); }
__device__ __forceinline__ void  stf(float* p, float v) { *p = v; }
__device__ __forceinline__ void  stf(bf16* p, float v)  { *p = __float2bfloat16(v); }

__device__ __forceinline__ short f2bs(float v) {
    bf16 t = __float2bfloat16(v); short s; __builtin_memcpy(&s, &t, 2); return s;
}
__device__ __forceinline__ float fsig(float x) {
    return __builtin_amdgcn_rcpf(1.f + __expf(-x));
}
__device__ __forceinline__ float ftanh(float x) {
    float t = __expf(-2.f * fabsf(x));
    float r = __builtin_amdgcn_rcpf(1.f + t);
    float m = 1.f - 2.f * t * r;
    return copysignf(m, x);
}
// packed f16 dual-FMA -> v_fma_mix_f32
__device__ __forceinline__ float fmix2(unsigned w, unsigned h, float acc) {
    half2v wv, hv;
    __builtin_memcpy(&wv, &w, 4);
    __builtin_memcpy(&hv, &h, 4);
    acc = fmaf((float)wv[0], (float)hv[0], acc);
    acc = fmaf((float)wv[1], (float)hv[1], acc);
    return acc;
}

__device__ __forceinline__ bf16x8 load8(const bf16* p) { return *(const bf16x8*)p; }
__device__ __forceinline__ bf16x8 load8(const float* p) {
    float4 x = *(const float4*)p;
    float4 y = *(const float4*)(p + 4);
    bf16x8 r;
    r[0] = f2bs(x.x); r[1] = f2bs(x.y); r[2] = f2bs(x.z); r[3] = f2bs(x.w);
    r[4] = f2bs(y.x); r[5] = f2bs(y.y); r[6] = f2bs(y.z); r[7] = f2bs(y.w);
    return r;
}

__global__ void zero_kernel(float* o, int n)
{
    int i = blockIdx.x * 256 + threadIdx.x;
    if (i < n) o[i] = 0.f;
}

// ---------------- fused preprocessing ----------------
__device__ __forceinline__ void body_cvt_bf16(const float* __restrict__ s, bf16* __restrict__ d,
                                              int i, int n4)
{
    if (i >= n4) return;
    float4 v = ((const float4*)s)[i];
    bf16x4 o;
    o[0] = f2bs(v.x); o[1] = f2bs(v.y); o[2] = f2bs(v.z); o[3] = f2bs(v.w);
    *(bf16x4*)(d + 4 * (size_t)i) = o;
}
__device__ __forceinline__ void body_cvt_f16(const float* __restrict__ s, f16* __restrict__ d,
                                             int i, int n4)
{
    if (i >= n4) return;
    float4 v = ((const float4*)s)[i];
    f16 o[4] = {(f16)v.x, (f16)v.y, (f16)v.z, (f16)v.w};
    *(uint2*)(d + 4 * (size_t)i) = *(uint2*)o;
}
__device__ __forceinline__ void body_wt(const float* __restrict__ w, bf16* __restrict__ WT, int idx)
{
    if (idx >= 129024) return;   // 9*4*112*32
    int i  = idx & 31;
    int oc = (idx >> 5) % 112;
    int ts = idx / (112 * 32);
    int s = ts & 3, t = ts >> 2;
    int ic = s * 32 + i;
    float v = 0.f;
    if (oc < OC && ic < OC) v = w[(oc * OC + ic) * 9 + t];
    WT[idx] = __float2bfloat16(v);
}

__global__ __launch_bounds__(256)
void prep_kernel(const float* __restrict__ x2,   bf16* __restrict__ X2B,
                 const float* __restrict__ whh0, f16*  __restrict__ LWf0,
                 const float* __restrict__ whh1, f16*  __restrict__ LWf1,
                 const float* __restrict__ wih0, bf16* __restrict__ WIH0B,
                 const float* __restrict__ wih1, bf16* __restrict__ WIH1B,
                 const float* __restrict__ a1w,  bf16* __restrict__ A1WB,
                 const float* __restrict__ bih0, const float* __restrict__ bhh0, float* __restrict__ BS0,
                 const float* __restrict__ bih1, const float* __restrict__ bhh1, float* __restrict__ BS1,
                 const float* __restrict__ c2aw, bf16* __restrict__ WTa,
                 const float* __restrict__ c2bw, bf16* __restrict__ WTb)
{
    int bid = blockIdx.x;
    int tid = threadIdx.x;
    if (bid < 2048)      body_cvt_bf16(x2,   X2B,   bid * 256 + tid, 524288);
    else if (bid < 2112) body_cvt_f16 (whh0, LWf0, (bid - 2048) * 256 + tid, 16384);
    else if (bid < 2176) body_cvt_f16 (whh1, LWf1, (bid - 2112) * 256 + tid, 16384);
    else if (bid < 2208) body_cvt_bf16(wih0, WIH0B, (bid - 2176) * 256 + tid, 8192);
    else if (bid < 2272) body_cvt_bf16(wih1, WIH1B, (bid - 2208) * 256 + tid, 16384);
    else if (bid < 2499) body_cvt_bf16(a1w,  A1WB,  (bid - 2272) * 256 + tid, 57920);
    else if (bid < 2500) { BS0[tid] = bih0[tid] + bhh0[tid]; BS0[tid + 256] = bih0[tid + 256] + bhh0[tid + 256]; }
    else if (bid < 2501) { BS1[tid] = bih1[tid] + bhh1[tid]; BS1[tid + 256] = bih1[tid + 256] + bhh1[tid + 256]; }
    else if (bid < 3005) body_wt(c2aw, WTa, (bid - 2501) * 256 + tid);
    else                 body_wt(c2bw, WTb, (bid - 3005) * 256 + tid);
}

// ---------------- conv1 body (wl/bl preloaded+synced by caller) ----------------
__device__ __forceinline__
void conv1_body(const float* __restrict__ x1, const float* __restrict__ wl,
                const float* __restrict__ bl, bf16* __restrict__ out, int b, int py, int t)
{
    int px = py * 256 + t;
    if (px >= NPX1) return;
    int y = px / W1, x = px % W1;
    float in[3][3][3];
    const float* xb = x1 + (size_t)b * 3 * 64 * 64;
#pragma unroll
    for (int ic = 0; ic < 3; ic++)
#pragma unroll
        for (int r = 0; r < 3; r++)
#pragma unroll
            for (int c = 0; c < 3; c++)
                in[ic][r][c] = xb[(ic * 64 + y + r) * 64 + x + c];
    bf16* ob = out + (size_t)b * OC * NPX1 + px;
    for (int oc = 0; oc < OC; ++oc) {
        float acc = bl[oc];
        const float* wp = &wl[oc * 27];
#pragma unroll
        for (int ic = 0; ic < 3; ic++)
#pragma unroll
            for (int r = 0; r < 3; r++)
#pragma unroll
                for (int c = 0; c < 3; c++)
                    acc = fmaf(in[ic][r][c], wp[ic * 9 + r * 3 + c], acc);
        ob[(size_t)oc * NPX1] = __float2bfloat16(fmaxf(acc, 0.f));
    }
}

__global__ __launch_bounds__(256)
void conv1_kernel(const float* __restrict__ x1, const float* __restrict__ w,
                  const float* __restrict__ bias, bf16* __restrict__ out)
{
    __shared__ float wl[2700];
    __shared__ float bl[OC];
    int tid = threadIdx.x;
    for (int i = tid; i < 2700; i += 256) wl[i] = w[i];
    if (tid < OC) bl[tid] = bias[tid];
    __syncthreads();
    conv1_body(x1, wl, bl, out, blockIdx.x, blockIdx.y, tid);
}

// ---------------- conv2 body (lane-ordered wl; r11 bank fix) ----------------
__device__ __forceinline__
void conv2_body(const bf16* __restrict__ in, const bf16* __restrict__ WT,
                const float* __restrict__ bias, bf16* __restrict__ out,
                int iw, int ow, int b, int yblk, int tid,
                bf16* __restrict__ il, bf16* __restrict__ wl)
{
    int y0 = yblk * 8;
    int wid = tid >> 6;
    int l = tid & 63;
    int hq = l >> 4;
    int l16 = l & 15;
    int yo = y0 + wid;

    f32x4 acc[7][4];
#pragma unroll
    for (int f = 0; f < 7; f++) {
#pragma unroll
        for (int r = 0; r < 4; r++) {
            int oc = f * 16 + hq * 4 + r;
            float bv = (oc < OC) ? bias[oc] : 0.f;
#pragma unroll
            for (int n = 0; n < 4; n++) acc[f][n][r] = bv;
        }
    }

    const size_t ims = (size_t)iw * iw;
    int icl = tid & 31;
    int t2  = tid >> 5;
    for (int s = 0; s < 4; ++s) {
        __syncthreads();
        int ic = s * 32 + icl;
        bool icok = ic < OC;
        const bf16* ibase = in + (size_t)(b * OC + ic) * ims;
#pragma unroll
        for (int it = 0; it < 6; ++it) {
            int u2 = t2 + it * 16;
            if (u2 < 90) {
                int r = u2 / 9, xb = u2 - r * 9;
                int x8 = xb * 8;
                int yy = y0 + r;
                bf16x8 v = {0, 0, 0, 0, 0, 0, 0, 0};
                if (icok && yy < iw && x8 < iw) {
                    const short* sp = (const short*)(ibase + (size_t)yy * iw + x8);
                    if (x8 + 8 <= iw) {
                        const unsigned* sp32 = (const unsigned*)sp;
#pragma unroll
                        for (int q = 0; q < 4; q++)
                            ((unsigned*)&v)[q] = sp32[q];
                    } else {
                        for (int k = 0; k < 8; k++)
                            if (x8 + k < iw) ((short*)&v)[k] = sp[k];
                    }
                }
                bf16* dst = &il[(r * 72 + x8) * 40 + icl];
#pragma unroll
                for (int k = 0; k < 8; k++)
                    *(short*)&dst[k * 40] = ((short*)&v)[k];
            }
        }
#pragma unroll
        for (int it = 0; it < 8; ++it) {
            int u = tid + it * 512;            // over 9*7*64 = 4032 units
            if (u < 4032) {
                int tf = u >> 6; int lp = u & 63;
                int t = tf / 7, f = tf - t * 7;
                int oc = f * 16 + (lp & 15);
                int hq2 = lp >> 4;
                *(bf16x8*)&wl[(size_t)u * 8] =
                    *(const bf16x8*)(WT + (size_t)((t * 4 + s) * 112 + oc) * 32 + hq2 * 8);
            }
        }
        __syncthreads();

#pragma unroll
        for (int ky = 0; ky < 3; ++ky) {
#pragma unroll
            for (int kx = 0; kx < 3; ++kx) {
                int t = ky * 3 + kx;
                bf16x8 a[7];
#pragma unroll
                for (int f = 0; f < 7; f++)
                    a[f] = *(const bf16x8*)&wl[(size_t)((t * 7 + f) * 64 + l) * 8];
                bf16x8 bfr[4];
#pragma unroll
                for (int n = 0; n < 4; n++)
                    bfr[n] = *(const bf16x8*)&il[((wid + ky) * 72 + kx + l16 + n * 16) * 40 + hq * 8];
#pragma unroll
                for (int f = 0; f < 7; f++)
#pragma unroll
                    for (int n = 0; n < 4; n++)
                        acc[f][n] = __builtin_amdgcn_mfma_f32_16x16x32_bf16(
                            a[f], bfr[n], acc[f][n], 0, 0, 0);
            }
        }
    }

    if (yo < ow) {
#pragma unroll
        for (int f = 0; f < 7; f++) {
#pragma unroll
            for (int r = 0; r < 4; r++) {
                int oc = f * 16 + hq * 4 + r;
                if (oc < OC) {
#pragma unroll
                    for (int n = 0; n < 4; n++) {
                        int x = n * 16 + l16;
                        if (x < ow)
                            out[((size_t)(b * OC + oc) * ow + yo) * ow + x] =
                                __float2bfloat16(fmaxf(acc[f][n][r], 0.f));
                    }
                }
            }
        }
    }
}

__global__ __launch_bounds__(512, 1)
void conv2_mfma(const bf16* __restrict__ in, const bf16* __restrict__ WT,
                const float* __restrict__ bias, bf16* __restrict__ out,
                int iw, int ow)
{
    __shared__ bf16 il[10 * 72 * 40];
    __shared__ bf16 wl[4032 * 8];
    conv2_body(in, WT, bias, out, iw, ow, blockIdx.x, blockIdx.y, threadIdx.x, il, wl);
}

// ---------------- LSTM body (r12 proven: f16 weights, pin, G-prefetch, 2 barriers) ----------------
__device__ __forceinline__
void lstm_body(const bf16* __restrict__ G, const f16* __restrict__ LWr,
               bf16* __restrict__ Y, float* __restrict__ HN, int hoff,
               int b, int g, f16* __restrict__ hl, float* __restrict__ ex)
{
    uint4 wv[16];
    const uint4* wp = (const uint4*)(LWr + (size_t)g * HD);
#pragma unroll
    for (int q = 0; q < 16; q++) wv[q] = wp[q];
#pragma unroll
    for (int q = 0; q < 16; q++)
        asm volatile("" : "+v"(wv[q].x), "+v"(wv[q].y), "+v"(wv[q].z), "+v"(wv[q].w));
    float c = 0.f;
    if (g < HD) hl[g] = (f16)0.f;
    __syncthreads();
    const bf16* Gb = G + (size_t)b * TT * G4 + g;
    float gcur = __bfloat162float(Gb[0]);
    for (int t = 0; t < TT; ++t) {
        int tn = (t + 1 < TT) ? t + 1 : t;
        bf16 gnext = Gb[(size_t)tn * G4];
        float a0 = 0.f, a1 = 0.f, a2 = 0.f, a3 = 0.f;
#pragma unroll
        for (int q = 0; q < 16; q++) {
            uint4 hw = *(const uint4*)&hl[q * 8];
            a0 = fmix2(wv[q].x, hw.x, a0);
            a1 = fmix2(wv[q].y, hw.y, a1);
            a2 = fmix2(wv[q].z, hw.z, a2);
            a3 = fmix2(wv[q].w, hw.w, a3);
        }
        float dot = gcur + (a0 + a1) + (a2 + a3);
        float tr;
        if (g < 2 * HD || g >= 3 * HD) tr = fsig(dot);
        else tr = ftanh(dot);
        ex[g] = tr;
        gcur = __bfloat162float(gnext);
        __syncthreads();
        if (g < HD) {
            float iv = ex[g], fv = ex[HD + g], gv = ex[2 * HD + g], ov = ex[3 * HD + g];
            c = fv * c + iv * gv;
            float nh = ov * ftanh(c);
            hl[g] = (f16)nh;
            if (Y) Y[((size_t)b * TT + t) * HD + g] = __float2bfloat16(nh);
            if (t == TT - 1) HN[(size_t)b * 256 + hoff + g] = nh;
        }
        __syncthreads();
    }
}

__global__ __launch_bounds__(512, 1)
void lstm_recur(const bf16* __restrict__ G, const f16* __restrict__ LWr,
                bf16* __restrict__ Y, float* __restrict__ HN, int hoff)
{
    __shared__ __align__(16) f16 hl[HD];
    __shared__ float ex[G4];
    lstm_body(G, LWr, Y, HN, hoff, blockIdx.x, threadIdx.x, hl, ex);
}

// ---------------- hybrid co-dispatch: lstm-layer0 (blocks 0..127) + conv1 (blocks 128+) ----------------
// conv1 writes A1c placed at base+92.16MB (disjoint from G0/Y0/X2B/weights).
__global__ __launch_bounds__(512, 1)
void hybrid_l0c1(const bf16* __restrict__ G, const f16* __restrict__ LWf0,
                 bf16* __restrict__ Y0, float* __restrict__ HN,
                 const float* __restrict__ x1, const float* __restrict__ c1w,
                 const float* __restrict__ c1b, bf16* __restrict__ A1)
{
    __shared__ __align__(16) char smem[11264];
    int bid = blockIdx.x;
    if (bid < BB) {
        lstm_body(G, LWf0, Y0, HN, 0, bid, threadIdx.x,
                  (f16*)smem, (float*)(smem + 512));
    } else {
        float* wl = (float*)smem;              // 2700 floats [0,10800)
        float* bl = (float*)(smem + 10800);    // 100 floats  [10800,11200)
        int tid = threadIdx.x;
        for (int i = tid; i < 2700; i += 512) wl[i] = c1w[i];
        if (tid < OC) bl[tid] = c1b[tid];
        __syncthreads();
        int v = (bid - BB) * 2 + (tid >> 8);   // 2 virtual 256-thr tiles / block
        conv1_body(x1, wl, bl, A1, v >> 4, v & 15, tid & 255);
    }
}

// ---------------- generic MFMA GEMM ----------------
template<typename TB, typename TC, int ACT>
__global__ __launch_bounds__(256)
void gemm_mfma(const bf16* __restrict__ A, int lda,
               const TB* __restrict__ B, int ldb,
               const float* __restrict__ bias,
               TC* __restrict__ C, int ldc,
               int M, int N, int K)
{
    __shared__ bf16 As[64 * 72];
    __shared__ bf16 Bs[64 * 72];
    int tid = threadIdx.x;
    int l = tid & 63, wid = tid >> 6;
    int l16 = l & 15, h = l >> 4;
    int m0 = blockIdx.x * 64, n0 = blockIdx.y * 64;
    f32x4 acc[4];
#pragma unroll
    for (int nb = 0; nb < 4; nb++) acc[nb] = (f32x4){0.f, 0.f, 0.f, 0.f};

    int rs = tid >> 3;
    int kc = (tid & 7) * 8;

    for (int k0 = 0; k0 < K; k0 += 64) {
        int kr = K - k0;
#pragma unroll
        for (int half = 0; half < 2; half++) {
            int rr = rs + half * 32;
            bf16x8 av = {0, 0, 0, 0, 0, 0, 0, 0};
            int m = m0 + rr;
            if (m < M) {
                const short* src = (const short*)(A + (size_t)m * lda + k0 + kc);
                if (kc + 8 <= kr) av = *(const bf16x8*)src;
                else if (kc < kr) {
                    for (int j = 0; j < 8; j++) if (kc + j < kr) ((short*)&av)[j] = src[j];
                }
            }
            *(bf16x8*)&As[rr * 72 + kc] = av;
            bf16x8 bv = {0, 0, 0, 0, 0, 0, 0, 0};
            int n = n0 + rr;
            if (n < N) {
                const TB* src = B + (size_t)n * ldb + k0 + kc;
                if (kc + 8 <= kr) bv = load8(src);
                else if (kc < kr) {
                    for (int j = 0; j < 8; j++) if (kc + j < kr) ((short*)&bv)[j] = f2bs(ldf(src + j));
                }
            }
            *(bf16x8*)&Bs[rr * 72 + kc] = bv;
        }
        __syncthreads();
#pragma unroll
        for (int kk = 0; kk < 2; kk++) {
            bf16x8 af = *(const bf16x8*)&As[(wid * 16 + l16) * 72 + kk * 32 + h * 8];
#pragma unroll
            for (int nb = 0; nb < 4; nb++) {
                bf16x8 bfr = *(const bf16x8*)&Bs[(nb * 16 + l16) * 72 + kk * 32 + h * 8];
                acc[nb] = __builtin_amdgcn_mfma_f32_16x16x32_bf16(af, bfr, acc[nb], 0, 0, 0);
            }
        }
        __syncthreads();
    }
#pragma unroll
    for (int nb = 0; nb < 4; nb++) {
        int col = n0 + nb * 16 + l16;
        if (col >= N) continue;
        float bv = bias ? bias[col] : 0.f;
#pragma unroll
        for (int reg = 0; reg < 4; reg++) {
            int row = m0 + wid * 16 + h * 4 + reg;
            if (row < M) {
                float v = acc[nb][reg] + bv;
                if (ACT == 1) v = fmaxf(v, 0.f);
                stf(&C[(size_t)row * ldc + col], v);
            }
        }
    }
}

// ---------------- small fp32 GEMM (tiny HB matmul) ----------------
template<typename TA, typename TC, int BM, int BN, int BK, int TM, int TN, int ACT>
__global__ __launch_bounds__((BM / TM) * (BN / TN))
void gemm_tn(const TA* __restrict__ A, int lda,
             const float* __restrict__ Bmat, int ldb,
             const float* __restrict__ bias,
             TC* __restrict__ C, int ldc,
             int M, int N, int K)
{
    constexpr int TX = BN / TN;
    constexpr int TY = BM / TM;
    constexpr int NT = TX * TY;
    __shared__ float As[BK][BM + 1];
    __shared__ float Bs[BK][BN + 1];
    int tid = threadIdx.x;
    int tx = tid % TX, ty = tid / TX;
    int m0 = blockIdx.x * BM, n0 = blockIdx.y * BN;
    float acc[TM][TN] = {};
    for (int k0 = 0; k0 < K; k0 += BK) {
        for (int idx = tid; idx < BM * BK; idx += NT) {
            int i = idx / BK, j = idx % BK;
            int m = m0 + i, k = k0 + j;
            As[j][i] = (m < M && k < K) ? ldf(&A[(size_t)m * lda + k]) : 0.f;
        }
        for (int idx = tid; idx < BN * BK; idx += NT) {
            int i = idx / BK, j = idx % BK;
            int n = n0 + i, k = k0 + j;
            Bs[j][i] = (n < N && k < K) ? Bmat[(size_t)n * ldb + k] : 0.f;
        }
        __syncthreads();
#pragma unroll
        for (int k = 0; k < BK; ++k) {
            float av[TM], bv[TN];
#pragma unroll
            for (int i = 0; i < TM; i++) av[i] = As[k][ty * TM + i];
#pragma unroll
            for (int j = 0; j < TN; j++) bv[j] = Bs[k][tx * TN + j];
#pragma unroll
            for (int i = 0; i < TM; i++)
#pragma unroll
                for (int j = 0; j < TN; j++)
                    acc[i][j] += av[i] * bv[j];
        }
        __syncthreads();
    }
#pragma unroll
    for (int i = 0; i < TM; i++) {
        int m = m0 + ty * TM + i;
        if (m >= M) continue;
#pragma unroll
        for (int j = 0; j < TN; j++) {
            int n = n0 + tx * TN + j;
            if (n >= N) continue;
            float v = acc[i][j] + (bias ? bias[n] : 0.f);
            if (ACT == 1) v = fmaxf(v, 0.f);
            stf(&C[(size_t)m * ldc + n], v);
        }
    }
}

// ---------------- small helpers ----------------
__global__ __launch_bounds__(128)
void attn_softmax(const float* __restrict__ T1,  // [nb*OC,64]
                  const float* __restrict__ HB,  // [nb,64]
                  const float* __restrict__ a2w,
                  const float* __restrict__ a2b,
                  float* __restrict__ ATT)       // [nb,100]
{
    __shared__ float hbl[ANF];
    __shared__ float awl[ANF];
    __shared__ float red[128];
    int b = blockIdx.x, tid = threadIdx.x;
    if (tid < ANF) { hbl[tid] = HB[b * ANF + tid]; awl[tid] = a2w[tid]; }
    __syncthreads();
    float lg = -1e30f;
    if (tid < OC) {
        const float* tp = T1 + (size_t)(b * OC + tid) * ANF;
        float s = 0.f;
#pragma unroll 4
        for (int j = 0; j < ANF; j++) s += ftanh(tp[j] + hbl[j]) * awl[j];
        lg = s + a2b[0];
    }
    red[tid] = lg; __syncthreads();
    for (int st = 64; st > 0; st >>= 1) { if (tid < st) red[tid] = fmaxf(red[tid], red[tid + st]); __syncthreads(); }
    float mx = red[0]; __syncthreads();
    float e = (tid < OC) ? __expf(lg - mx) : 0.f;
    red[tid] = e; __syncthreads();
    for (int st = 64; st > 0; st >>= 1) { if (tid < st) red[tid] += red[tid + st]; __syncthreads(); }
    if (tid < OC) ATT[b * OC + tid] = e / red[0];
}

__global__ __launch_bounds__(256)
void ctx_concat(const bf16* __restrict__ XD,   // [nb,100,3364]
                const float* __restrict__ ATT, // [nb,100]
                const float* __restrict__ HN,  // [nb,256] (chunk base)
                bf16* __restrict__ M)          // [nb,3620] bf16 (chunk base)
{
    __shared__ float al[OC];
    int b = blockIdx.x;
    int tid = threadIdx.x;
    if (tid < OC) al[tid] = ATT[b * OC + tid];
    __syncthreads();
    int s = blockIdx.y * 256 + tid;
    if (s < SS) {
        const bf16* xp = XD + (size_t)b * OC * SS + s;
        float acc = 0.f;
#pragma unroll 4
        for (int c = 0; c < OC; c++) acc = fmaf(__bfloat162float(xp[(size_t)c * SS]), al[c], acc);
        M[(size_t)b * FF + s] = __float2bfloat16(acc);
    } else if (s < FF) {
        M[(size_t)b * FF + s] = __float2bfloat16(HN[b * 256 + (s - SS)]);
    }
}

__global__ __launch_bounds__(256)
void fc2_kernel(const float* __restrict__ H1, const float* __restrict__ w,
                const float* __restrict__ bias, float* __restrict__ out)
{
    int tid = threadIdx.x;
    int lane = tid & 63, wid = tid >> 6;
    int b = blockIdx.x * 4 + wid;
    float acc = 0.f;
    for (int j = lane; j < HIDN; j += 64) acc = fmaf(H1[(size_t)b * HIDN + j], w[j], acc);
#pragma unroll
    for (int off = 32; off > 0; off >>= 1) acc += __shfl_down(acc, off, 64);
    if (lane == 0) out[b] = acc + bias[0];
}

extern "C" void kernel_launch(void* const* d_in, const int* in_sizes, int n_in,
                              void* d_out, int out_size, void* d_ws, size_t ws_size,
                              hipStream_t stream)
{
    const float* x1   = (const float*)d_in[0];
    const float* x2   = (const float*)d_in[1];
    const float* c1w  = (const float*)d_in[2];
    const float* c1b  = (const float*)d_in[3];
    const float* c2aw = (const float*)d_in[4];
    const float* c2ab = (const float*)d_in[5];
    const float* c2bw = (const float*)d_in[6];
    const float* c2bb = (const float*)d_in[7];
    const float* wih0 = (const float*)d_in[8];
    const float* whh0 = (const float*)d_in[9];
    const float* bih0 = (const float*)d_in[10];
    const float* bhh0 = (const float*)d_in[11];
    const float* wih1 = (const float*)d_in[12];
    const float* whh1 = (const float*)d_in[13];
    const float* bih1 = (const float*)d_in[14];
    const float* bhh1 = (const float*)d_in[15];
    const float* a1w  = (const float*)d_in[16];
    const float* a1b  = (const float*)d_in[17];
    const float* a2w  = (const float*)d_in[18];
    const float* a2b  = (const float*)d_in[19];
    const float* f1w  = (const float*)d_in[20];
    const float* f1b  = (const float*)d_in[21];
    const float* f2w  = (const float*)d_in[22];
    const float* f2b  = (const float*)d_in[23];
    float* out = (float*)d_out;

    // ---- LSTM-phase overlay (fixed offsets) ----
    char* base = (char*)d_ws;
    bf16* G0    = (bf16*)(base + 0);            // 33,554,432
    bf16* Y0    = (bf16*)(base + 33554432);     //  8,388,608
    bf16* G1    = G0;                           // reuse
    bf16* X2B   = (bf16*)(base + 41943040);     //  4,194,304
    bf16* WIH0B = (bf16*)(base + 46137344);     //     65,536
    bf16* WIH1B = (bf16*)(base + 46202880);     //    131,072
    f16*  LWf0  = (f16*)(base + 46333952);      //    131,072
    f16*  LWf1  = (f16*)(base + 46465024);      //    131,072 (end 46,596,096)
    const size_t LSTM_END = 46596096;

    // ---- pick CNN batch-chunk size from available workspace ----
    int nb = 0; size_t ov = 0;
    for (int cand = BB; cand >= 32; cand >>= 1) {
        size_t cnn = (size_t)cand * OC * (NPX1 + NPX2) * 2;
        size_t o = cnn > LSTM_END ? cnn : LSTM_END;
        size_t q = o + 2048 + 2048 + 131072 + 32768
                 + (size_t)cand * OC * 64 * 4
                 + (((size_t)cand * OC * 4 + 255) & ~(size_t)255)
                 + 926720 + 926720 + 258048 + 258048 + 463360;
        if (ws_size >= q) { nb = cand; ov = o; break; }
    }
    if (nb == 0) {
        zero_kernel<<<1, 128, 0, stream>>>(out, out_size);
        return;
    }
    // Hybrid layout (nb==128): A2c at [0, 92.16MB) is written only AFTER lstm1
    // retires (G0/Y0 dead); A1c at [92.16, 190.57MB) is written by hybrid0's
    // conv1 -- disjoint from G0 [0,33.5M), Y0 [33.5,41.9M), weights [46.1,46.6M).
    // cnn(128) = 190,566,400 = ov, so A1c end == ov fits the verified budget.
    bf16* A1c;
    bf16* A2c;
    if (nb == BB) {
        A2c = (bf16*)(base + 0);                               // 92,160,000 B
        A1c = (bf16*)(base + (size_t)BB * OC * NPX2 * 2);      // 98,406,400 B @ 92,160,000
    } else {
        A1c = (bf16*)(base + 0);
        A2c = (bf16*)(base + (size_t)nb * OC * NPX1 * 2);
    }
    bf16* XDc = A1c;
    size_t p = ov;
    float* BS0  = (float*)(base + p); p += 2048;
    float* BS1  = (float*)(base + p); p += 2048;
    float* HN   = (float*)(base + p); p += 131072;
    float* HB   = (float*)(base + p); p += 32768;
    float* T1c  = (float*)(base + p); p += (size_t)nb * OC * 64 * 4;
    float* ATTc = (float*)(base + p); p += ((size_t)nb * OC * 4 + 255) & ~(size_t)255;
    bf16*  MBb  = (bf16*)(base + p); p += 926720;
    float* H1   = (float*)(base + p); p += 926720;
    bf16* WTa   = (bf16*)(base + p); p += 258048;
    bf16* WTb   = (bf16*)(base + p); p += 258048;
    bf16* A1WB  = (bf16*)(base + p); p += 463360;

    // ---- fused preprocessing ----
    prep_kernel<<<3509, 256, 0, stream>>>(
        x2, X2B, whh0, LWf0, whh1, LWf1, wih0, WIH0B, wih1, WIH1B, a1w, A1WB,
        bih0, bhh0, BS0, bih1, bhh1, BS1, c2aw, WTa, c2bw, WTb);

    // ---- gate GEMM (layer0 x-part) ----
    gemm_mfma<bf16, bf16, 0><<<dim3(512, 8), 256, 0, stream>>>(
        X2B, IDIM, WIH0B, IDIM, BS0, G0, G4, BB * TT, G4, IDIM);

    if (nb == BB) {
        // co-dispatch: lstm-layer0 + conv1(full batch)  [A1c disjoint from LSTM bufs]
        hybrid_l0c1<<<BB + BB * 8, 512, 0, stream>>>(
            G0, LWf0, Y0, HN, x1, c1w, c1b, A1c);
        // layer1 gate GEMM, then layer1 recurrence (standalone; no co-writes to G0)
        gemm_mfma<bf16, bf16, 0><<<dim3(512, 8), 256, 0, stream>>>(
            Y0, HD, WIH1B, HD, BS1, G1, G4, BB * TT, G4, HD);
        lstm_recur<<<BB, 512, 0, stream>>>(G1, LWf1, (bf16*)nullptr, HN, HD);
        // CNN tail: G0/Y0 now dead -> A2c at base+0 is safe
        conv2_mfma<<<dim3(BB, 8), 512, 0, stream>>>(A1c, WTa, c2ab, A2c, W1, W2);
        conv2_mfma<<<dim3(BB, 8), 512, 0, stream>>>(A2c, WTb, c2bb, XDc, W2, W3);
        gemm_tn<float, float, 32, 32, 16, 2, 2, 0><<<dim3(4, 2), 256, 0, stream>>>(
            HN, 256, a1w + SS, FF, a1b, HB, ANF, BB, ANF, 256);
        gemm_mfma<bf16, float, 0><<<dim3(BB * OC / 64, 1), 256, 0, stream>>>(
            XDc, SS, A1WB, FF, nullptr, T1c, ANF, BB * OC, ANF, SS);
        attn_softmax<<<BB, 128, 0, stream>>>(T1c, HB, a2w, a2b, ATTc);
        ctx_concat<<<dim3(BB, 15), 256, 0, stream>>>(XDc, ATTc, HN, MBb);
    } else {
        // fallback: flat r12 sequence
        lstm_recur<<<BB, 512, 0, stream>>>(G0, LWf0, Y0, HN, 0);
        gemm_mfma<bf16, bf16, 0><<<dim3(512, 8), 256, 0, stream>>>(
            Y0, HD, WIH1B, HD, BS1, G1, G4, BB * TT, G4, HD);
        lstm_recur<<<BB, 512, 0, stream>>>(G1, LWf1, (bf16*)nullptr, HN, HD);
        gemm_tn<float, float, 32, 32, 16, 2, 2, 0><<<dim3(4, 2), 256, 0, stream>>>(
            HN, 256, a1w + SS, FF, a1b, HB, ANF, BB, ANF, 256);
        for (int c0 = 0; c0 < BB; c0 += nb) {
            conv1_kernel<<<dim3(nb, 16), 256, 0, stream>>>(
                x1 + (size_t)c0 * 3 * 64 * 64, c1w, c1b, A1c);
            conv2_mfma<<<dim3(nb, 8), 512, 0, stream>>>(A1c, WTa, c2ab, A2c, W1, W2);
            conv2_mfma<<<dim3(nb, 8), 512, 0, stream>>>(A2c, WTb, c2bb, XDc, W2, W3);
            gemm_mfma<bf16, float, 0><<<dim3(nb * OC / 64, 1), 256, 0, stream>>>(
                XDc, SS, A1WB, FF, nullptr, T1c, ANF, nb * OC, ANF, SS);
            attn_softmax<<<nb, 128, 0, stream>>>(T1c, HB + (size_t)c0 * ANF, a2w, a2b, ATTc);
            ctx_concat<<<dim3(nb, 15), 256, 0, stream>>>(
                XDc, ATTc, HN + (size_t)c0 * 256, MBb + (size_t)c0 * FF);
        }
    }

    // ---- fusion MLP ----
    gemm_mfma<float, float, 1><<<dim3(2, 29), 256, 0, stream>>>(
        MBb, FF, f1w, FF, f1b, H1, HIDN, BB, HIDN, FF);
    fc2_kernel<<<BB / 4, 256, 0, stream>>>(H1, f2w, f2b, out);
}

// Round 16
// 1054.304 us; speedup vs baseline: 15.3931x; 1.0419x over previous
//
#include <hip/hip_runtime.h>
#include <hip/hip_bf16.h>
#include <math.h>

#define BB 128
#define TT 256
#define IDIM 64
#define HD 128
#define G4 512
#define OC 100
#define W1 62
#define W2 60
#define W3 58
#define NPX1 (W1*W1)
#define NPX2 (W2*W2)
#define NPX3 (W3*W3)
#define SS NPX3
#define FF (SS + 2*HD)
#define HIDN 1810
#define ANF 64
#define ROWSPLIT 47   // conv2a rows >= ROWSPLIT are disjoint from G0 (47*720000 > 33.55MB)

typedef __hip_bfloat16 bf16;
typedef _Float16 f16;
typedef __attribute__((ext_vector_type(8))) short bf16x8;
typedef __attribute__((ext_vector_type(4))) short bf16x4;
typedef __attribute__((ext_vector_type(2))) _Float16 half2v;
typedef __attribute__((ext_vector_type(4))) float f32x4;

__device__ __forceinline__ float ldf(const float* p) { return *p; }
__device__ __forceinline__ float ldf(const bf16* p)  { return __bfloat162float(*p); }
__device__ __forceinline__ void  stf(float* p, float v) { *p = v; }
__device__ __forceinline__ void  stf(bf16* p, float v)  { *p = __float2bfloat16(v); }

__device__ __forceinline__ short f2bs(float v) {
    bf16 t = __float2bfloat16(v); short s; __builtin_memcpy(&s, &t, 2); return s;
}
__device__ __forceinline__ float fsig(float x) {
    return __builtin_amdgcn_rcpf(1.f + __expf(-x));
}
__device__ __forceinline__ float ftanh(float x) {
    float t = __expf(-2.f * fabsf(x));
    float r = __builtin_amdgcn_rcpf(1.f + t);
    float m = 1.f - 2.f * t * r;
    return copysignf(m, x);
}
// packed f16 dual-FMA -> v_fma_mix_f32
__device__ __forceinline__ float fmix2(unsigned w, unsigned h, float acc) {
    half2v wv, hv;
    __builtin_memcpy(&wv, &w, 4);
    __builtin_memcpy(&hv, &h, 4);
    acc = fmaf((float)wv[0], (float)hv[0], acc);
    acc = fmaf((float)wv[1], (float)hv[1], acc);
    return acc;
}

__device__ __forceinline__ bf16x8 load8(const bf16* p) { return *(const bf16x8*)p; }
__device__ __forceinline__ bf16x8 load8(const float* p) {
    float4 x = *(const float4*)p;
    float4 y = *(const float4*)(p + 4);
    bf16x8 r;
    r[0] = f2bs(x.x); r[1] = f2bs(x.y); r[2] = f2bs(x.z); r[3] = f2bs(x.w);
    r[4] = f2bs(y.x); r[5] = f2bs(y.y); r[6] = f2bs(y.z); r[7] = f2bs(y.w);
    return r;
}

__global__ void zero_kernel(float* o, int n)
{
    int i = blockIdx.x * 256 + threadIdx.x;
    if (i < n) o[i] = 0.f;
}

// ---------------- fused preprocessing ----------------
__device__ __forceinline__ void body_cvt_bf16(const float* __restrict__ s, bf16* __restrict__ d,
                                              int i, int n4)
{
    if (i >= n4) return;
    float4 v = ((const float4*)s)[i];
    bf16x4 o;
    o[0] = f2bs(v.x); o[1] = f2bs(v.y); o[2] = f2bs(v.z); o[3] = f2bs(v.w);
    *(bf16x4*)(d + 4 * (size_t)i) = o;
}
__device__ __forceinline__ void body_cvt_f16(const float* __restrict__ s, f16* __restrict__ d,
                                             int i, int n4)
{
    if (i >= n4) return;
    float4 v = ((const float4*)s)[i];
    f16 o[4] = {(f16)v.x, (f16)v.y, (f16)v.z, (f16)v.w};
    *(uint2*)(d + 4 * (size_t)i) = *(uint2*)o;
}
__device__ __forceinline__ void body_wt(const float* __restrict__ w, bf16* __restrict__ WT, int idx)
{
    if (idx >= 129024) return;   // 9*4*112*32
    int i  = idx & 31;
    int oc = (idx >> 5) % 112;
    int ts = idx / (112 * 32);
    int s = ts & 3, t = ts >> 2;
    int ic = s * 32 + i;
    float v = 0.f;
    if (oc < OC && ic < OC) v = w[(oc * OC + ic) * 9 + t];
    WT[idx] = __float2bfloat16(v);
}

__global__ __launch_bounds__(256)
void prep_kernel(const float* __restrict__ x2,   bf16* __restrict__ X2B,
                 const float* __restrict__ whh0, f16*  __restrict__ LWf0,
                 const float* __restrict__ whh1, f16*  __restrict__ LWf1,
                 const float* __restrict__ wih0, bf16* __restrict__ WIH0B,
                 const float* __restrict__ wih1, bf16* __restrict__ WIH1B,
                 const float* __restrict__ a1w,  bf16* __restrict__ A1WB,
                 const float* __restrict__ bih0, const float* __restrict__ bhh0, float* __restrict__ BS0,
                 const float* __restrict__ bih1, const float* __restrict__ bhh1, float* __restrict__ BS1,
                 const float* __restrict__ c2aw, bf16* __restrict__ WTa,
                 const float* __restrict__ c2bw, bf16* __restrict__ WTb)
{
    int bid = blockIdx.x;
    int tid = threadIdx.x;
    if (bid < 2048)      body_cvt_bf16(x2,   X2B,   bid * 256 + tid, 524288);
    else if (bid < 2112) body_cvt_f16 (whh0, LWf0, (bid - 2048) * 256 + tid, 16384);
    else if (bid < 2176) body_cvt_f16 (whh1, LWf1, (bid - 2112) * 256 + tid, 16384);
    else if (bid < 2208) body_cvt_bf16(wih0, WIH0B, (bid - 2176) * 256 + tid, 8192);
    else if (bid < 2272) body_cvt_bf16(wih1, WIH1B, (bid - 2208) * 256 + tid, 16384);
    else if (bid < 2499) body_cvt_bf16(a1w,  A1WB,  (bid - 2272) * 256 + tid, 57920);
    else if (bid < 2500) { BS0[tid] = bih0[tid] + bhh0[tid]; BS0[tid + 256] = bih0[tid + 256] + bhh0[tid + 256]; }
    else if (bid < 2501) { BS1[tid] = bih1[tid] + bhh1[tid]; BS1[tid + 256] = bih1[tid + 256] + bhh1[tid + 256]; }
    else if (bid < 3005) body_wt(c2aw, WTa, (bid - 2501) * 256 + tid);
    else                 body_wt(c2bw, WTb, (bid - 3005) * 256 + tid);
}

// ---------------- conv1 body (wl/bl preloaded+synced by caller) ----------------
__device__ __forceinline__
void conv1_body(const float* __restrict__ x1, const float* __restrict__ wl,
                const float* __restrict__ bl, bf16* __restrict__ out, int b, int py, int t)
{
    int px = py * 256 + t;
    if (px >= NPX1) return;
    int y = px / W1, x = px % W1;
    float in[3][3][3];
    const float* xb = x1 + (size_t)b * 3 * 64 * 64;
#pragma unroll
    for (int ic = 0; ic < 3; ic++)
#pragma unroll
        for (int r = 0; r < 3; r++)
#pragma unroll
            for (int c = 0; c < 3; c++)
                in[ic][r][c] = xb[(ic * 64 + y + r) * 64 + x + c];
    bf16* ob = out + (size_t)b * OC * NPX1 + px;
    for (int oc = 0; oc < OC; ++oc) {
        float acc = bl[oc];
        const float* wp = &wl[oc * 27];
#pragma unroll
        for (int ic = 0; ic < 3; ic++)
#pragma unroll
            for (int r = 0; r < 3; r++)
#pragma unroll
                for (int c = 0; c < 3; c++)
                    acc = fmaf(in[ic][r][c], wp[ic * 9 + r * 3 + c], acc);
        ob[(size_t)oc * NPX1] = __float2bfloat16(fmaxf(acc, 0.f));
    }
}

__global__ __launch_bounds__(256)
void conv1_kernel(const float* __restrict__ x1, const float* __restrict__ w,
                  const float* __restrict__ bias, bf16* __restrict__ out)
{
    __shared__ float wl[2700];
    __shared__ float bl[OC];
    int tid = threadIdx.x;
    for (int i = tid; i < 2700; i += 256) wl[i] = w[i];
    if (tid < OC) bl[tid] = bias[tid];
    __syncthreads();
    conv1_body(x1, wl, bl, out, blockIdx.x, blockIdx.y, tid);
}

// ---------------- conv2 body (lane-ordered wl; r11 bank fix) ----------------
__device__ __forceinline__
void conv2_body(const bf16* __restrict__ in, const bf16* __restrict__ WT,
                const float* __restrict__ bias, bf16* __restrict__ out,
                int iw, int ow, int b, int yblk, int tid,
                bf16* __restrict__ il, bf16* __restrict__ wl)
{
    int y0 = yblk * 8;
    int wid = tid >> 6;
    int l = tid & 63;
    int hq = l >> 4;
    int l16 = l & 15;
    int yo = y0 + wid;

    f32x4 acc[7][4];
#pragma unroll
    for (int f = 0; f < 7; f++) {
#pragma unroll
        for (int r = 0; r < 4; r++) {
            int oc = f * 16 + hq * 4 + r;
            float bv = (oc < OC) ? bias[oc] : 0.f;
#pragma unroll
            for (int n = 0; n < 4; n++) acc[f][n][r] = bv;
        }
    }

    const size_t ims = (size_t)iw * iw;
    int icl = tid & 31;
    int t2  = tid >> 5;
    for (int s = 0; s < 4; ++s) {
        __syncthreads();
        int ic = s * 32 + icl;
        bool icok = ic < OC;
        const bf16* ibase = in + (size_t)(b * OC + ic) * ims;
#pragma unroll
        for (int it = 0; it < 6; ++it) {
            int u2 = t2 + it * 16;
            if (u2 < 90) {
                int r = u2 / 9, xb = u2 - r * 9;
                int x8 = xb * 8;
                int yy = y0 + r;
                bf16x8 v = {0, 0, 0, 0, 0, 0, 0, 0};
                if (icok && yy < iw && x8 < iw) {
                    const short* sp = (const short*)(ibase + (size_t)yy * iw + x8);
                    if (x8 + 8 <= iw) {
                        const unsigned* sp32 = (const unsigned*)sp;
#pragma unroll
                        for (int q = 0; q < 4; q++)
                            ((unsigned*)&v)[q] = sp32[q];
                    } else {
                        for (int k = 0; k < 8; k++)
                            if (x8 + k < iw) ((short*)&v)[k] = sp[k];
                    }
                }
                bf16* dst = &il[(r * 72 + x8) * 40 + icl];
#pragma unroll
                for (int k = 0; k < 8; k++)
                    *(short*)&dst[k * 40] = ((short*)&v)[k];
            }
        }
#pragma unroll
        for (int it = 0; it < 8; ++it) {
            int u = tid + it * 512;            // over 9*7*64 = 4032 units
            if (u < 4032) {
                int tf = u >> 6; int lp = u & 63;
                int t = tf / 7, f = tf - t * 7;
                int oc = f * 16 + (lp & 15);
                int hq2 = lp >> 4;
                *(bf16x8*)&wl[(size_t)u * 8] =
                    *(const bf16x8*)(WT + (size_t)((t * 4 + s) * 112 + oc) * 32 + hq2 * 8);
            }
        }
        __syncthreads();

#pragma unroll
        for (int ky = 0; ky < 3; ++ky) {
#pragma unroll
            for (int kx = 0; kx < 3; ++kx) {
                int t = ky * 3 + kx;
                bf16x8 a[7];
#pragma unroll
                for (int f = 0; f < 7; f++)
                    a[f] = *(const bf16x8*)&wl[(size_t)((t * 7 + f) * 64 + l) * 8];
                bf16x8 bfr[4];
#pragma unroll
                for (int n = 0; n < 4; n++)
                    bfr[n] = *(const bf16x8*)&il[((wid + ky) * 72 + kx + l16 + n * 16) * 40 + hq * 8];
#pragma unroll
                for (int f = 0; f < 7; f++)
#pragma unroll
                    for (int n = 0; n < 4; n++)
                        acc[f][n] = __builtin_amdgcn_mfma_f32_16x16x32_bf16(
                            a[f], bfr[n], acc[f][n], 0, 0, 0);
            }
        }
    }

    if (yo < ow) {
#pragma unroll
        for (int f = 0; f < 7; f++) {
#pragma unroll
            for (int r = 0; r < 4; r++) {
                int oc = f * 16 + hq * 4 + r;
                if (oc < OC) {
#pragma unroll
                    for (int n = 0; n < 4; n++) {
                        int x = n * 16 + l16;
                        if (x < ow)
                            out[((size_t)(b * OC + oc) * ow + yo) * ow + x] =
                                __float2bfloat16(fmaxf(acc[f][n][r], 0.f));
                    }
                }
            }
        }
    }
}

__global__ __launch_bounds__(512, 1)
void conv2_mfma(const bf16* __restrict__ in, const bf16* __restrict__ WT,
                const float* __restrict__ bias, bf16* __restrict__ out,
                int iw, int ow, int brow0)
{
    __shared__ bf16 il[10 * 72 * 40];
    __shared__ bf16 wl[4032 * 8];
    conv2_body(in, WT, bias, out, iw, ow, brow0 + blockIdx.x, blockIdx.y, threadIdx.x, il, wl);
}

// ---------------- LSTM body (r12 proven) ----------------
__device__ __forceinline__
void lstm_body(const bf16* __restrict__ G, const f16* __restrict__ LWr,
               bf16* __restrict__ Y, float* __restrict__ HN, int hoff,
               int b, int g, f16* __restrict__ hl, float* __restrict__ ex)
{
    uint4 wv[16];
    const uint4* wp = (const uint4*)(LWr + (size_t)g * HD);
#pragma unroll
    for (int q = 0; q < 16; q++) wv[q] = wp[q];
#pragma unroll
    for (int q = 0; q < 16; q++)
        asm volatile("" : "+v"(wv[q].x), "+v"(wv[q].y), "+v"(wv[q].z), "+v"(wv[q].w));
    float c = 0.f;
    if (g < HD) hl[g] = (f16)0.f;
    __syncthreads();
    const bf16* Gb = G + (size_t)b * TT * G4 + g;
    float gcur = __bfloat162float(Gb[0]);
    for (int t = 0; t < TT; ++t) {
        int tn = (t + 1 < TT) ? t + 1 : t;
        bf16 gnext = Gb[(size_t)tn * G4];
        float a0 = 0.f, a1 = 0.f, a2 = 0.f, a3 = 0.f;
#pragma unroll
        for (int q = 0; q < 16; q++) {
            uint4 hw = *(const uint4*)&hl[q * 8];
            a0 = fmix2(wv[q].x, hw.x, a0);
            a1 = fmix2(wv[q].y, hw.y, a1);
            a2 = fmix2(wv[q].z, hw.z, a2);
            a3 = fmix2(wv[q].w, hw.w, a3);
        }
        float dot = gcur + (a0 + a1) + (a2 + a3);
        float tr;
        if (g < 2 * HD || g >= 3 * HD) tr = fsig(dot);
        else tr = ftanh(dot);
        ex[g] = tr;
        gcur = __bfloat162float(gnext);
        __syncthreads();
        if (g < HD) {
            float iv = ex[g], fv = ex[HD + g], gv = ex[2 * HD + g], ov = ex[3 * HD + g];
            c = fv * c + iv * gv;
            float nh = ov * ftanh(c);
            hl[g] = (f16)nh;
            if (Y) Y[((size_t)b * TT + t) * HD + g] = __float2bfloat16(nh);
            if (t == TT - 1) HN[(size_t)b * 256 + hoff + g] = nh;
        }
        __syncthreads();
    }
}

__global__ __launch_bounds__(512, 1)
void lstm_recur(const bf16* __restrict__ G, const f16* __restrict__ LWr,
                bf16* __restrict__ Y, float* __restrict__ HN, int hoff)
{
    __shared__ __align__(16) f16 hl[HD];
    __shared__ float ex[G4];
    lstm_body(G, LWr, Y, HN, hoff, blockIdx.x, threadIdx.x, hl, ex);
}

// ---------------- hybrid: lstm-layer0 (blocks 0..127) + conv1 (blocks 128+) ----------------
__global__ __launch_bounds__(512, 1)
void hybrid_l0c1(const bf16* __restrict__ G, const f16* __restrict__ LWf0,
                 bf16* __restrict__ Y0, float* __restrict__ HN,
                 const float* __restrict__ x1, const float* __restrict__ c1w,
                 const float* __restrict__ c1b, bf16* __restrict__ A1)
{
    __shared__ __align__(16) char smem[11264];
    int bid = blockIdx.x;
    if (bid < BB) {
        lstm_body(G, LWf0, Y0, HN, 0, bid, threadIdx.x,
                  (f16*)smem, (float*)(smem + 512));
    } else {
        float* wl = (float*)smem;
        float* bl = (float*)(smem + 10800);
        int tid = threadIdx.x;
        for (int i = tid; i < 2700; i += 512) wl[i] = c1w[i];
        if (tid < OC) bl[tid] = c1b[tid];
        __syncthreads();
        int v = (bid - BB) * 2 + (tid >> 8);
        conv1_body(x1, wl, bl, A1, v >> 4, v & 15, tid & 255);
    }
}

// ---------------- hybrid: lstm-layer1 (blocks 0..127) + conv2a rows>=ROWSPLIT ----------------
// conv writes A2c rows [ROWSPLIT,128) = bytes [33.84MB, 92.16MB): disjoint from
// live G1=G0 [0,33.55MB). LWf1/WTa/HN/A1c live in tail/high regions (disjoint).
__global__ __launch_bounds__(512, 1)
void hybrid_l1c2a(const bf16* __restrict__ G, const f16* __restrict__ LWf1,
                  float* __restrict__ HN,
                  const bf16* __restrict__ A1, const bf16* __restrict__ WTa,
                  const float* __restrict__ c2ab, bf16* __restrict__ A2)
{
    __shared__ __align__(16) char smem[122112];
    int bid = blockIdx.x;
    if (bid < BB) {
        lstm_body(G, LWf1, (bf16*)nullptr, HN, HD, bid, threadIdx.x,
                  (f16*)smem, (float*)(smem + 512));
    } else {
        int r = bid - BB;                      // [0, (128-ROWSPLIT)*8)
        conv2_body(A1, WTa, c2ab, A2, W1, W2, ROWSPLIT + (r >> 3), r & 7,
                   threadIdx.x, (bf16*)smem, (bf16*)(smem + 57600));
    }
}

// ---------------- generic MFMA GEMM ----------------
template<typename TB, typename TC, int ACT>
__global__ __launch_bounds__(256)
void gemm_mfma(const bf16* __restrict__ A, int lda,
               const TB* __restrict__ B, int ldb,
               const float* __restrict__ bias,
               TC* __restrict__ C, int ldc,
               int M, int N, int K)
{
    __shared__ bf16 As[64 * 72];
    __shared__ bf16 Bs[64 * 72];
    int tid = threadIdx.x;
    int l = tid & 63, wid = tid >> 6;
    int l16 = l & 15, h = l >> 4;
    int m0 = blockIdx.x * 64, n0 = blockIdx.y * 64;
    f32x4 acc[4];
#pragma unroll
    for (int nb = 0; nb < 4; nb++) acc[nb] = (f32x4){0.f, 0.f, 0.f, 0.f};

    int rs = tid >> 3;
    int kc = (tid & 7) * 8;

    for (int k0 = 0; k0 < K; k0 += 64) {
        int kr = K - k0;
#pragma unroll
        for (int half = 0; half < 2; half++) {
            int rr = rs + half * 32;
            bf16x8 av = {0, 0, 0, 0, 0, 0, 0, 0};
            int m = m0 + rr;
            if (m < M) {
                const short* src = (const short*)(A + (size_t)m * lda + k0 + kc);
                if (kc + 8 <= kr) av = *(const bf16x8*)src;
                else if (kc < kr) {
                    for (int j = 0; j < 8; j++) if (kc + j < kr) ((short*)&av)[j] = src[j];
                }
            }
            *(bf16x8*)&As[rr * 72 + kc] = av;
            bf16x8 bv = {0, 0, 0, 0, 0, 0, 0, 0};
            int n = n0 + rr;
            if (n < N) {
                const TB* src = B + (size_t)n * ldb + k0 + kc;
                if (kc + 8 <= kr) bv = load8(src);
                else if (kc < kr) {
                    for (int j = 0; j < 8; j++) if (kc + j < kr) ((short*)&bv)[j] = f2bs(ldf(src + j));
                }
            }
            *(bf16x8*)&Bs[rr * 72 + kc] = bv;
        }
        __syncthreads();
#pragma unroll
        for (int kk = 0; kk < 2; kk++) {
            bf16x8 af = *(const bf16x8*)&As[(wid * 16 + l16) * 72 + kk * 32 + h * 8];
#pragma unroll
            for (int nb = 0; nb < 4; nb++) {
                bf16x8 bfr = *(const bf16x8*)&Bs[(nb * 16 + l16) * 72 + kk * 32 + h * 8];
                acc[nb] = __builtin_amdgcn_mfma_f32_16x16x32_bf16(af, bfr, acc[nb], 0, 0, 0);
            }
        }
        __syncthreads();
    }
#pragma unroll
    for (int nb = 0; nb < 4; nb++) {
        int col = n0 + nb * 16 + l16;
        if (col >= N) continue;
        float bv = bias ? bias[col] : 0.f;
#pragma unroll
        for (int reg = 0; reg < 4; reg++) {
            int row = m0 + wid * 16 + h * 4 + reg;
            if (row < M) {
                float v = acc[nb][reg] + bv;
                if (ACT == 1) v = fmaxf(v, 0.f);
                stf(&C[(size_t)row * ldc + col], v);
            }
        }
    }
}

// ---------------- small fp32 GEMM (tiny HB matmul) ----------------
template<typename TA, typename TC, int BM, int BN, int BK, int TM, int TN, int ACT>
__global__ __launch_bounds__((BM / TM) * (BN / TN))
void gemm_tn(const TA* __restrict__ A, int lda,
             const float* __restrict__ Bmat, int ldb,
             const float* __restrict__ bias,
             TC* __restrict__ C, int ldc,
             int M, int N, int K)
{
    constexpr int TX = BN / TN;
    constexpr int TY = BM / TM;
    constexpr int NT = TX * TY;
    __shared__ float As[BK][BM + 1];
    __shared__ float Bs[BK][BN + 1];
    int tid = threadIdx.x;
    int tx = tid % TX, ty = tid / TX;
    int m0 = blockIdx.x * BM, n0 = blockIdx.y * BN;
    float acc[TM][TN] = {};
    for (int k0 = 0; k0 < K; k0 += BK) {
        for (int idx = tid; idx < BM * BK; idx += NT) {
            int i = idx / BK, j = idx % BK;
            int m = m0 + i, k = k0 + j;
            As[j][i] = (m < M && k < K) ? ldf(&A[(size_t)m * lda + k]) : 0.f;
        }
        for (int idx = tid; idx < BN * BK; idx += NT) {
            int i = idx / BK, j = idx % BK;
            int n = n0 + i, k = k0 + j;
            Bs[j][i] = (n < N && k < K) ? Bmat[(size_t)n * ldb + k] : 0.f;
        }
        __syncthreads();
#pragma unroll
        for (int k = 0; k < BK; ++k) {
            float av[TM], bv[TN];
#pragma unroll
            for (int i = 0; i < TM; i++) av[i] = As[k][ty * TM + i];
#pragma unroll
            for (int j = 0; j < TN; j++) bv[j] = Bs[k][tx * TN + j];
#pragma unroll
            for (int i = 0; i < TM; i++)
#pragma unroll
                for (int j = 0; j < TN; j++)
                    acc[i][j] += av[i] * bv[j];
        }
        __syncthreads();
    }
#pragma unroll
    for (int i = 0; i < TM; i++) {
        int m = m0 + ty * TM + i;
        if (m >= M) continue;
#pragma unroll
        for (int j = 0; j < TN; j++) {
            int n = n0 + tx * TN + j;
            if (n >= N) continue;
            float v = acc[i][j] + (bias ? bias[n] : 0.f);
            if (ACT == 1) v = fmaxf(v, 0.f);
            stf(&C[(size_t)m * ldc + n], v);
        }
    }
}

// ---------------- small helpers ----------------
__global__ __launch_bounds__(128)
void attn_softmax(const float* __restrict__ T1,
                  const float* __restrict__ HB,
                  const float* __restrict__ a2w,
                  const float* __restrict__ a2b,
                  float* __restrict__ ATT)
{
    __shared__ float hbl[ANF];
    __shared__ float awl[ANF];
    __shared__ float red[128];
    int b = blockIdx.x, tid = threadIdx.x;
    if (tid < ANF) { hbl[tid] = HB[b * ANF + tid]; awl[tid] = a2w[tid]; }
    __syncthreads();
    float lg = -1e30f;
    if (tid < OC) {
        const float* tp = T1 + (size_t)(b * OC + tid) * ANF;
        float s = 0.f;
#pragma unroll 4
        for (int j = 0; j < ANF; j++) s += ftanh(tp[j] + hbl[j]) * awl[j];
        lg = s + a2b[0];
    }
    red[tid] = lg; __syncthreads();
    for (int st = 64; st > 0; st >>= 1) { if (tid < st) red[tid] = fmaxf(red[tid], red[tid + st]); __syncthreads(); }
    float mx = red[0]; __syncthreads();
    float e = (tid < OC) ? __expf(lg - mx) : 0.f;
    red[tid] = e; __syncthreads();
    for (int st = 64; st > 0; st >>= 1) { if (tid < st) red[tid] += red[tid + st]; __syncthreads(); }
    if (tid < OC) ATT[b * OC + tid] = e / red[0];
}

__global__ __launch_bounds__(256)
void ctx_concat(const bf16* __restrict__ XD,
                const float* __restrict__ ATT,
                const float* __restrict__ HN,
                bf16* __restrict__ M)
{
    __shared__ float al[OC];
    int b = blockIdx.x;
    int tid = threadIdx.x;
    if (tid < OC) al[tid] = ATT[b * OC + tid];
    __syncthreads();
    int s = blockIdx.y * 256 + tid;
    if (s < SS) {
        const bf16* xp = XD + (size_t)b * OC * SS + s;
        float acc = 0.f;
#pragma unroll 4
        for (int c = 0; c < OC; c++) acc = fmaf(__bfloat162float(xp[(size_t)c * SS]), al[c], acc);
        M[(size_t)b * FF + s] = __float2bfloat16(acc);
    } else if (s < FF) {
        M[(size_t)b * FF + s] = __float2bfloat16(HN[b * 256 + (s - SS)]);
    }
}

__global__ __launch_bounds__(256)
void fc2_kernel(const float* __restrict__ H1, const float* __restrict__ w,
                const float* __restrict__ bias, float* __restrict__ out)
{
    int tid = threadIdx.x;
    int lane = tid & 63, wid = tid >> 6;
    int b = blockIdx.x * 4 + wid;
    float acc = 0.f;
    for (int j = lane; j < HIDN; j += 64) acc = fmaf(H1[(size_t)b * HIDN + j], w[j], acc);
#pragma unroll
    for (int off = 32; off > 0; off >>= 1) acc += __shfl_down(acc, off, 64);
    if (lane == 0) out[b] = acc + bias[0];
}

extern "C" void kernel_launch(void* const* d_in, const int* in_sizes, int n_in,
                              void* d_out, int out_size, void* d_ws, size_t ws_size,
                              hipStream_t stream)
{
    const float* x1   = (const float*)d_in[0];
    const float* x2   = (const float*)d_in[1];
    const float* c1w  = (const float*)d_in[2];
    const float* c1b  = (const float*)d_in[3];
    const float* c2aw = (const float*)d_in[4];
    const float* c2ab = (const float*)d_in[5];
    const float* c2bw = (const float*)d_in[6];
    const float* c2bb = (const float*)d_in[7];
    const float* wih0 = (const float*)d_in[8];
    const float* whh0 = (const float*)d_in[9];
    const float* bih0 = (const float*)d_in[10];
    const float* bhh0 = (const float*)d_in[11];
    const float* wih1 = (const float*)d_in[12];
    const float* whh1 = (const float*)d_in[13];
    const float* bih1 = (const float*)d_in[14];
    const float* bhh1 = (const float*)d_in[15];
    const float* a1w  = (const float*)d_in[16];
    const float* a1b  = (const float*)d_in[17];
    const float* a2w  = (const float*)d_in[18];
    const float* a2b  = (const float*)d_in[19];
    const float* f1w  = (const float*)d_in[20];
    const float* f1b  = (const float*)d_in[21];
    const float* f2w  = (const float*)d_in[22];
    const float* f2b  = (const float*)d_in[23];
    float* out = (float*)d_out;

    // ---- LSTM-phase overlay (LWf0/LWf1 moved to tail: conv2a rows>=47 during
    // hybrid_l1c2a overwrite [33.84M, 92.16M) which would hit the old LWf slots) ----
    char* base = (char*)d_ws;
    bf16* G0    = (bf16*)(base + 0);            // 33,554,432
    bf16* Y0    = (bf16*)(base + 33554432);     //  8,388,608
    bf16* G1    = G0;                           // reuse
    bf16* X2B   = (bf16*)(base + 41943040);     //  4,194,304
    bf16* WIH0B = (bf16*)(base + 46137344);     //     65,536
    bf16* WIH1B = (bf16*)(base + 46202880);     //    131,072 (end 46,333,952)
    const size_t LSTM_END = 46333952;

    // ---- pick CNN batch-chunk size from available workspace ----
    int nb = 0; size_t ov = 0;
    for (int cand = BB; cand >= 32; cand >>= 1) {
        size_t cnn = (size_t)cand * OC * (NPX1 + NPX2) * 2;
        size_t o = cnn > LSTM_END ? cnn : LSTM_END;
        size_t q = o + 2048 + 2048 + 131072 + 32768
                 + (size_t)cand * OC * 64 * 4
                 + (((size_t)cand * OC * 4 + 255) & ~(size_t)255)
                 + 926720 + 926720 + 258048 + 258048 + 463360
                 + 262144;                                         // LWf0+LWf1 in tail
        if (ws_size >= q) { nb = cand; ov = o; break; }
    }
    if (nb == 0) {
        zero_kernel<<<1, 128, 0, stream>>>(out, out_size);
        return;
    }
    bf16* A1c;
    bf16* A2c;
    if (nb == BB) {
        A2c = (bf16*)(base + 0);                               // 92,160,000 B
        A1c = (bf16*)(base + (size_t)BB * OC * NPX2 * 2);      // @92.16M, 98.4MB
    } else {
        A1c = (bf16*)(base + 0);
        A2c = (bf16*)(base + (size_t)nb * OC * NPX1 * 2);
    }
    bf16* XDc = A1c;
    size_t p = ov;
    float* BS0  = (float*)(base + p); p += 2048;
    float* BS1  = (float*)(base + p); p += 2048;
    float* HN   = (float*)(base + p); p += 131072;
    float* HB   = (float*)(base + p); p += 32768;
    float* T1c  = (float*)(base + p); p += (size_t)nb * OC * 64 * 4;
    float* ATTc = (float*)(base + p); p += ((size_t)nb * OC * 4 + 255) & ~(size_t)255;
    bf16*  MBb  = (bf16*)(base + p); p += 926720;
    float* H1   = (float*)(base + p); p += 926720;
    bf16* WTa   = (bf16*)(base + p); p += 258048;
    bf16* WTb   = (bf16*)(base + p); p += 258048;
    bf16* A1WB  = (bf16*)(base + p); p += 463360;
    f16*  LWf0  = (f16*)(base + p); p += 131072;   // tail: safe from conv writes
    f16*  LWf1  = (f16*)(base + p); p += 131072;

    // ---- fused preprocessing ----
    prep_kernel<<<3509, 256, 0, stream>>>(
        x2, X2B, whh0, LWf0, whh1, LWf1, wih0, WIH0B, wih1, WIH1B, a1w, A1WB,
        bih0, bhh0, BS0, bih1, bhh1, BS1, c2aw, WTa, c2bw, WTb);

    // ---- gate GEMM (layer0 x-part) ----
    gemm_mfma<bf16, bf16, 0><<<dim3(512, 8), 256, 0, stream>>>(
        X2B, IDIM, WIH0B, IDIM, BS0, G0, G4, BB * TT, G4, IDIM);

    if (nb == BB) {
        // lstm-layer0 + conv1 (A1c @92.16M disjoint from LSTM bufs)
        hybrid_l0c1<<<BB + BB * 8, 512, 0, stream>>>(
            G0, LWf0, Y0, HN, x1, c1w, c1b, A1c);
        // layer1 gate GEMM (consumes Y0 -> G1)
        gemm_mfma<bf16, bf16, 0><<<dim3(512, 8), 256, 0, stream>>>(
            Y0, HD, WIH1B, HD, BS1, G1, G4, BB * TT, G4, HD);
        // lstm-layer1 + conv2a rows [ROWSPLIT,128): writes [33.84M,92.16M), G0-safe
        hybrid_l1c2a<<<BB + (BB - ROWSPLIT) * 8, 512, 0, stream>>>(
            G1, LWf1, HN, A1c, WTa, c2ab, A2c);
        // conv2a rows [0,ROWSPLIT): G0 dead now
        conv2_mfma<<<dim3(ROWSPLIT, 8), 512, 0, stream>>>(A1c, WTa, c2ab, A2c, W1, W2, 0);
        conv2_mfma<<<dim3(BB, 8), 512, 0, stream>>>(A2c, WTb, c2bb, XDc, W2, W3, 0);
        gemm_tn<float, float, 32, 32, 16, 2, 2, 0><<<dim3(4, 2), 256, 0, stream>>>(
            HN, 256, a1w + SS, FF, a1b, HB, ANF, BB, ANF, 256);
        gemm_mfma<bf16, float, 0><<<dim3(BB * OC / 64, 1), 256, 0, stream>>>(
            XDc, SS, A1WB, FF, nullptr, T1c, ANF, BB * OC, ANF, SS);
        attn_softmax<<<BB, 128, 0, stream>>>(T1c, HB, a2w, a2b, ATTc);
        ctx_concat<<<dim3(BB, 15), 256, 0, stream>>>(XDc, ATTc, HN, MBb);
    } else {
        // fallback: flat r12 sequence
        lstm_recur<<<BB, 512, 0, stream>>>(G0, LWf0, Y0, HN, 0);
        gemm_mfma<bf16, bf16, 0><<<dim3(512, 8), 256, 0, stream>>>(
            Y0, HD, WIH1B, HD, BS1, G1, G4, BB * TT, G4, HD);
        lstm_recur<<<BB, 512, 0, stream>>>(G1, LWf1, (bf16*)nullptr, HN, HD);
        gemm_tn<float, float, 32, 32, 16, 2, 2, 0><<<dim3(4, 2), 256, 0, stream>>>(
            HN, 256, a1w + SS, FF, a1b, HB, ANF, BB, ANF, 256);
        for (int c0 = 0; c0 < BB; c0 += nb) {
            conv1_kernel<<<dim3(nb, 16), 256, 0, stream>>>(
                x1 + (size_t)c0 * 3 * 64 * 64, c1w, c1b, A1c);
            conv2_mfma<<<dim3(nb, 8), 512, 0, stream>>>(A1c, WTa, c2ab, A2c, W1, W2, 0);
            conv2_mfma<<<dim3(nb, 8), 512, 0, stream>>>(A2c, WTb, c2bb, XDc, W2, W3, 0);
            gemm_mfma<bf16, float, 0><<<dim3(nb * OC / 64, 1), 256, 0, stream>>>(
                XDc, SS, A1WB, FF, nullptr, T1c, ANF, nb * OC, ANF, SS);
            attn_softmax<<<nb, 128, 0, stream>>>(T1c, HB + (size_t)c0 * ANF, a2w, a2b, ATTc);
            ctx_concat<<<dim3(nb, 15), 256, 0, stream>>>(
                XDc, ATTc, HN + (size_t)c0 * 256, MBb + (size_t)c0 * FF);
        }
    }

    // ---- fusion MLP ----
    gemm_mfma<float, float, 1><<<dim3(2, 29), 256, 0, stream>>>(
        MBb, FF, f1w, FF, f1b, H1, HIDN, BB, HIDN, FF);
    fc2_kernel<<<BB / 4, 256, 0, stream>>>(H1, f2w, f2b, out);
}